// Round 2
// baseline (2177.338 us; speedup 1.0000x reference)
//
#include <hip/hip_runtime.h>
#include <hip/hip_bf16.h>
#include <cstdint>

#define DH 128   // hidden dim
#define NH 4     // heads
#define HC 32    // head channels

// ---------------- zero-fill (avoid hipMemsetAsync in capture) ----------------

__global__ void zero_i32(int* __restrict__ p, int n) {
  int i = blockIdx.x * 256 + threadIdx.x;
  if (i < n) p[i] = 0;
}
__global__ void zero_f32(float* __restrict__ p, int n) {
  int i = blockIdx.x * 256 + threadIdx.x;
  if (i < n) p[i] = 0.f;
}

// ---------------- CSR build ----------------

__global__ void hist_kernel(const int* __restrict__ dst, int* __restrict__ deg, int E) {
  int e = blockIdx.x * 256 + threadIdx.x;
  if (e < E) atomicAdd(&deg[dst[e]], 1);
}

__global__ void scan1_kernel(const int* __restrict__ deg, int* __restrict__ off,
                             int* __restrict__ bsum, int n) {
  __shared__ int sh[256];
  int idx = blockIdx.x * 256 + threadIdx.x;
  int v = (idx < n) ? deg[idx] : 0;
  sh[threadIdx.x] = v;
  __syncthreads();
  for (int d = 1; d < 256; d <<= 1) {
    int x = (threadIdx.x >= (unsigned)d) ? sh[threadIdx.x - d] : 0;
    __syncthreads();
    sh[threadIdx.x] += x;
    __syncthreads();
  }
  if (idx < n) off[idx] = sh[threadIdx.x] - v;   // exclusive
  if (threadIdx.x == 255) bsum[blockIdx.x] = sh[255];
}

__global__ void scan2_kernel(int* __restrict__ bsum, int nb) {
  __shared__ int sh[512];
  int t = threadIdx.x;
  int v = (t < nb) ? bsum[t] : 0;
  sh[t] = v;
  __syncthreads();
  for (int d = 1; d < 512; d <<= 1) {
    int x = (t >= (unsigned)d) ? sh[t - d] : 0;
    __syncthreads();
    sh[t] += x;
    __syncthreads();
  }
  if (t < nb) bsum[t] = sh[t] - v;   // exclusive block offsets
}

__global__ void scan3_kernel(int* __restrict__ off, const int* __restrict__ bsum, int n) {
  int idx = blockIdx.x * 256 + threadIdx.x;
  if (idx < n) off[idx] += bsum[blockIdx.x];
}

__global__ void scatter_kernel(const int* __restrict__ src, const int* __restrict__ dst,
                               const int* __restrict__ off, int* __restrict__ cursor,
                               int* __restrict__ csr, int E) {
  int e = blockIdx.x * 256 + threadIdx.x;
  if (e < E) {
    int d = dst[e];
    int p = off[d] + atomicAdd(&cursor[d], 1);
    csr[p] = src[e];
  }
}

// ---------------- weight packing: Wcat[128][512] = [Wq|Wk|Wv|Ws] ----------------

__global__ void pack_w_kernel(const float* __restrict__ Wq, const float* __restrict__ Wk,
                              const float* __restrict__ Wv, const float* __restrict__ Ws,
                              const float* __restrict__ bq, const float* __restrict__ bk,
                              const float* __restrict__ bv, const float* __restrict__ bs,
                              float* __restrict__ Wcat, float* __restrict__ bcat) {
  int idx = blockIdx.x * 256 + threadIdx.x;
  if (idx < DH * 4 * DH) {
    int k = idx >> 9, c = idx & 511;
    int which = c >> 7, cc = c & 127;
    const float* W = (which == 0) ? Wq : (which == 1) ? Wk : (which == 2) ? Wv : Ws;
    Wcat[idx] = W[k * DH + cc];
    if (k == 0) {
      const float* b = (which == 0) ? bq : (which == 1) ? bk : (which == 2) ? bv : bs;
      bcat[c] = b[cc];
    }
  }
}

// ---------------- fused QKVS GEMM ----------------
// out = X[N,128] @ Wcat[128,512] + bcat, scattered to q (f32), kv (bf16), xr (f32).
// 64x64 tile, 256 threads, 4x4 micro-tile per thread, fp32.
// Each block's 64-col range lies entirely in one of the q/k/v/xr segments.

__global__ __launch_bounds__(256)
void gemm_qkvs(const float* __restrict__ X, const float* __restrict__ Wc,
               const float* __restrict__ bc, float* __restrict__ qout,
               __hip_bfloat16* __restrict__ kvout, float* __restrict__ xrout, int Nn) {
  __shared__ float As[16][68];   // [k][m], padded
  __shared__ float Bs[16][64];   // [k][n]
  const int row0 = blockIdx.x * 64;
  const int col0 = blockIdx.y * 64;
  const int tid = threadIdx.x;
  const int tm = tid >> 4;   // 0..15
  const int tn = tid & 15;   // 0..15
  float acc[4][4] = {{0.f}};

  for (int k0 = 0; k0 < 128; k0 += 16) {
#pragma unroll
    for (int i = 0; i < 4; ++i) {
      int lm = (tid >> 4) + i * 16;     // row within tile
      int lk = tid & 15;                // k within tile
      int row = row0 + lm; if (row >= Nn) row = Nn - 1;
      As[lk][lm] = X[(size_t)row * 128 + k0 + lk];
    }
#pragma unroll
    for (int i = 0; i < 4; ++i) {
      int lk = (tid >> 6) + i * 4;
      int lc = tid & 63;
      Bs[lk][lc] = Wc[(size_t)(k0 + lk) * 512 + col0 + lc];
    }
    __syncthreads();
#pragma unroll
    for (int kk = 0; kk < 16; ++kk) {
      float4 a = *(const float4*)&As[kk][tm * 4];
      float4 b = *(const float4*)&Bs[kk][tn * 4];
      acc[0][0] += a.x * b.x; acc[0][1] += a.x * b.y; acc[0][2] += a.x * b.z; acc[0][3] += a.x * b.w;
      acc[1][0] += a.y * b.x; acc[1][1] += a.y * b.y; acc[1][2] += a.y * b.z; acc[1][3] += a.y * b.w;
      acc[2][0] += a.z * b.x; acc[2][1] += a.z * b.y; acc[2][2] += a.z * b.z; acc[2][3] += a.z * b.w;
      acc[3][0] += a.w * b.x; acc[3][1] += a.w * b.y; acc[3][2] += a.w * b.z; acc[3][3] += a.w * b.w;
    }
    __syncthreads();
  }

  const int seg = col0 >> 7;          // 0=q 1=k 2=v 3=xr
  const int cbase = col0 & 127;       // column offset within segment
#pragma unroll
  for (int i = 0; i < 4; ++i) {
    int row = row0 + tm * 4 + i;
    if (row >= Nn) continue;
#pragma unroll
    for (int j = 0; j < 4; ++j) {
      int lc = tn * 4 + j;
      float v = acc[i][j] + bc[col0 + lc];
      int c = cbase + lc;             // 0..127 within segment
      if (seg == 0) {
        qout[(size_t)row * 128 + c] = v;
      } else if (seg == 1) {
        kvout[(size_t)row * 256 + c] = __float2bfloat16(v);
      } else if (seg == 2) {
        kvout[(size_t)row * 256 + 128 + c] = __float2bfloat16(v);
      } else {
        xrout[(size_t)row * 128 + c] = v;
      }
    }
  }
}

// ---------------- per-node attention + beta gate + relu ----------------
// block = 128 threads (1 feature each; head = t/32); one node per block.
// Writes h IN PLACE over q (q[i]/xr[i] are private to block i).

__global__ __launch_bounds__(128)
void attn_kernel(float* __restrict__ q_h, const __hip_bfloat16* __restrict__ kv,
                 const float* __restrict__ xrbuf, const int* __restrict__ off,
                 const int* __restrict__ deg, const int* __restrict__ csr,
                 const float* __restrict__ Wb, int Nn) {
  int i = blockIdx.x;
  int t = threadIdx.x;
  float q = q_h[(size_t)i * 128 + t];
  float xr = xrbuf[(size_t)i * 128 + t];
  int e0 = off[i];
  int e1 = e0 + deg[i];

  float m = -INFINITY, denom = 0.f, acc = 0.f;
  for (int e = e0; e < e1; ++e) {
    int s = csr[e];
    const __hip_bfloat16* ps = kv + (size_t)s * 256;
    float kvv = __bfloat162float(ps[t]);
    float vv = __bfloat162float(ps[128 + t]);
    float prod = q * kvv;
    prod += __shfl_xor(prod, 16);
    prod += __shfl_xor(prod, 8);
    prod += __shfl_xor(prod, 4);
    prod += __shfl_xor(prod, 2);
    prod += __shfl_xor(prod, 1);
    float alpha = prod * 0.17677669529663687f;   // 1/sqrt(32)
    float nm = fmaxf(m, alpha);
    float scale = __expf(m - nm);   // exp(-inf)=0 on first iter
    float p = __expf(alpha - nm);
    denom = denom * scale + p;
    acc = acc * scale + p * vv;
    m = nm;
  }
  float outv = acc / (denom + 1e-16f);

  // beta = sigmoid([out | xr | out-xr] . Wb)
  float c = outv * Wb[t] + xr * Wb[128 + t] + (outv - xr) * Wb[256 + t];
  c += __shfl_xor(c, 32);
  c += __shfl_xor(c, 16);
  c += __shfl_xor(c, 8);
  c += __shfl_xor(c, 4);
  c += __shfl_xor(c, 2);
  c += __shfl_xor(c, 1);
  __shared__ float red[2];
  if ((t & 63) == 0) red[t >> 6] = c;
  __syncthreads();
  float logit = red[0] + red[1];
  float beta = 1.f / (1.f + __expf(-logit));
  float h = beta * xr + (1.f - beta) * outv;
  q_h[(size_t)i * 128 + t] = fmaxf(h, 0.f);
}

// ---------------- global mean pool ----------------

__global__ void pool_kernel(const float* __restrict__ h, const int* __restrict__ batch,
                            float* __restrict__ gsum, float* __restrict__ gcnt, int Nn) {
  int idx = blockIdx.x * 256 + threadIdx.x;
  int n = idx >> 7;
  int f = idx & 127;
  if (n < Nn) {
    int g = batch[n];
    atomicAdd(&gsum[(size_t)g * DH + f], h[(size_t)n * DH + f]);
    if (f == 0) atomicAdd(&gcnt[g], 1.0f);
  }
}

// ---------------- MLP head: one block (128 thr) per graph ----------------

__global__ __launch_bounds__(128)
void mlp_kernel(const float* __restrict__ gsum, const float* __restrict__ gcnt,
                const float* __restrict__ W1, const float* __restrict__ b1,
                const float* __restrict__ W2, const float* __restrict__ b2,
                const float* __restrict__ W3, const float* __restrict__ b3,
                float* __restrict__ out) {
  int g = blockIdx.x;
  int t = threadIdx.x;
  __shared__ float gv[128];
  __shared__ float t1[64];
  __shared__ float t2[32];
  float cnt = fmaxf(gcnt[g], 1.0f);
  gv[t] = gsum[(size_t)g * DH + t] / cnt;
  __syncthreads();
  if (t < 64) {
    float s = b1[t];
    for (int k = 0; k < 128; ++k) s += gv[k] * W1[k * 64 + t];
    t1[t] = fmaxf(s, 0.f);
  }
  __syncthreads();
  if (t < 32) {
    float s = b2[t];
    for (int k = 0; k < 64; ++k) s += t1[k] * W2[k * 32 + t];
    t2[t] = fmaxf(s, 0.f);
  }
  __syncthreads();
  if (t == 0) {
    float s = b3[0];
    for (int k = 0; k < 32; ++k) s += t2[k] * W3[k];
    out[g] = 1.f / (1.f + __expf(-s));
  }
}

// ---------------- launch ----------------

extern "C" void kernel_launch(void* const* d_in, const int* in_sizes, int n_in,
                              void* d_out, int out_size, void* d_ws, size_t ws_size,
                              hipStream_t stream) {
  const float* x = (const float*)d_in[0];
  const int* edge_index = (const int*)d_in[1];
  const int* batch = (const int*)d_in[2];
  const int N = in_sizes[0] / DH;
  const int E = in_sizes[1] / 2;
  const int G = out_size;
  const int* src = edge_index;
  const int* dst = edge_index + E;

  const float* in_Wq = (const float*)d_in[3];
  const float* in_bq = (const float*)d_in[4];
  const float* in_Wk = (const float*)d_in[5];
  const float* in_bk = (const float*)d_in[6];
  const float* in_Wv = (const float*)d_in[7];
  const float* in_bv = (const float*)d_in[8];
  const float* in_Ws = (const float*)d_in[9];
  const float* in_bs = (const float*)d_in[10];
  const float* in_Wbeta = (const float*)d_in[11];
  const float* blk_Wq = (const float*)d_in[12];
  const float* blk_bq = (const float*)d_in[13];
  const float* blk_Wk = (const float*)d_in[14];
  const float* blk_bk = (const float*)d_in[15];
  const float* blk_Wv = (const float*)d_in[16];
  const float* blk_bv = (const float*)d_in[17];
  const float* blk_Ws = (const float*)d_in[18];
  const float* blk_bs = (const float*)d_in[19];
  const float* blk_Wbeta = (const float*)d_in[20];

  // workspace carve (256B aligned) — total ~213 MB
  char* p = (char*)d_ws;
  auto take = [&](size_t bytes) { char* r = p; p += (bytes + 255) & ~(size_t)255; return r; };
  float* Q0   = (float*)take((size_t)N * DH * 4);          // q / h ping
  float* Q1   = (float*)take((size_t)N * DH * 4);          // q / h pong
  float* xr   = (float*)take((size_t)N * DH * 4);
  __hip_bfloat16* kv = (__hip_bfloat16*)take((size_t)N * 256 * 2);
  float* Wcat = (float*)take((size_t)DH * 512 * 4);
  float* bcat = (float*)take(512 * 4);
  int*   deg  = (int*)take((size_t)N * 4);
  int*   off  = (int*)take((size_t)N * 4);
  int*   cursor = (int*)take((size_t)N * 4);
  int*   bsum = (int*)take(512 * 4);
  int*   csr  = (int*)take((size_t)E * 4);
  float* gsum = (float*)take((size_t)G * DH * 4);
  float* gcnt = (float*)take((size_t)G * 4);
  (void)n_in;
  if ((size_t)(p - (char*)d_ws) > ws_size) return;  // clean fail instead of fault

  int eb = (E + 255) / 256;
  int nb = (N + 255) / 256;
  zero_i32<<<nb, 256, 0, stream>>>(deg, N);
  zero_i32<<<nb, 256, 0, stream>>>(cursor, N);
  zero_f32<<<(G * DH + 255) / 256, 256, 0, stream>>>(gsum, G * DH);
  zero_f32<<<(G + 255) / 256, 256, 0, stream>>>(gcnt, G);

  hist_kernel<<<eb, 256, 0, stream>>>(dst, deg, E);
  scan1_kernel<<<nb, 256, 0, stream>>>(deg, off, bsum, N);
  scan2_kernel<<<1, 512, 0, stream>>>(bsum, nb);
  scan3_kernel<<<nb, 256, 0, stream>>>(off, bsum, N);
  scatter_kernel<<<eb, 256, 0, stream>>>(src, dst, off, cursor, csr, E);

  const float* hin = x;
  for (int l = 0; l < 4; ++l) {
    const float *Wq, *Wk, *Wv, *Ws, *bq, *bk, *bv, *bs, *Wb;
    if (l == 0) {
      Wq = in_Wq; Wk = in_Wk; Wv = in_Wv; Ws = in_Ws;
      bq = in_bq; bk = in_bk; bv = in_bv; bs = in_bs; Wb = in_Wbeta;
    } else {
      int m = l - 1;
      Wq = blk_Wq + (size_t)m * DH * DH; Wk = blk_Wk + (size_t)m * DH * DH;
      Wv = blk_Wv + (size_t)m * DH * DH; Ws = blk_Ws + (size_t)m * DH * DH;
      bq = blk_bq + (size_t)m * DH; bk = blk_bk + (size_t)m * DH;
      bv = blk_bv + (size_t)m * DH; bs = blk_bs + (size_t)m * DH;
      Wb = blk_Wbeta + (size_t)m * 3 * DH;
    }
    float* qbuf = (l & 1) ? Q1 : Q0;   // layer0: x->Q0, layer1: Q0->Q1, ...
    pack_w_kernel<<<(DH * 4 * DH + 255) / 256, 256, 0, stream>>>(Wq, Wk, Wv, Ws, bq, bk, bv, bs, Wcat, bcat);
    dim3 gg((N + 63) / 64, 8);
    gemm_qkvs<<<gg, 256, 0, stream>>>(hin, Wcat, bcat, qbuf, kv, xr, N);
    attn_kernel<<<N, 128, 0, stream>>>(qbuf, kv, xr, off, deg, csr, Wb, N);
    hin = qbuf;   // h was written in place over q
  }

  pool_kernel<<<(int)(((size_t)N * DH + 255) / 256), 256, 0, stream>>>(hin, batch, gsum, gcnt, N);
  mlp_kernel<<<G, 128, 0, stream>>>(gsum, gcnt,
      (const float*)d_in[21], (const float*)d_in[22],
      (const float*)d_in[23], (const float*)d_in[24],
      (const float*)d_in[25], (const float*)d_in[26],
      (float*)d_out);
}

// Round 3
// 1280.781 us; speedup vs baseline: 1.7000x; 1.7000x over previous
//
#include <hip/hip_runtime.h>
#include <hip/hip_bf16.h>
#include <cstdint>

#define DH 128   // hidden dim
#define NH 4     // heads
#define HC 32    // head channels

typedef __attribute__((ext_vector_type(8))) short short8;
typedef __attribute__((ext_vector_type(4))) float floatx4;

__device__ __forceinline__ float bfu2f(unsigned u) { return __uint_as_float(u << 16); }
__device__ __forceinline__ float bfh2f(unsigned u) { return __uint_as_float(u & 0xffff0000u); }

// ---------------- zero-fill (no hipMemsetAsync in capture) ----------------

__global__ void zero_i32(int* __restrict__ p, int n) {
  int i = blockIdx.x * 256 + threadIdx.x;
  if (i < n) p[i] = 0;
}
__global__ void zero_f32(float* __restrict__ p, int n) {
  int i = blockIdx.x * 256 + threadIdx.x;
  if (i < n) p[i] = 0.f;
}

// ---------------- fp32 -> bf16 convert ----------------

__global__ void cvt_bf16(const float* __restrict__ x, __hip_bfloat16* __restrict__ o, int n) {
  int i = blockIdx.x * 256 + threadIdx.x;
  if (i < n) o[i] = __float2bfloat16(x[i]);
}

// ---------------- CSR build ----------------

__global__ void hist_kernel(const int* __restrict__ dst, int* __restrict__ deg, int E) {
  int e = blockIdx.x * 256 + threadIdx.x;
  if (e < E) atomicAdd(&deg[dst[e]], 1);
}

__global__ void scan1_kernel(const int* __restrict__ deg, int* __restrict__ off,
                             int* __restrict__ bsum, int n) {
  __shared__ int sh[256];
  int idx = blockIdx.x * 256 + threadIdx.x;
  int v = (idx < n) ? deg[idx] : 0;
  sh[threadIdx.x] = v;
  __syncthreads();
  for (int d = 1; d < 256; d <<= 1) {
    int x = (threadIdx.x >= (unsigned)d) ? sh[threadIdx.x - d] : 0;
    __syncthreads();
    sh[threadIdx.x] += x;
    __syncthreads();
  }
  if (idx < n) off[idx] = sh[threadIdx.x] - v;   // exclusive
  if (threadIdx.x == 255) bsum[blockIdx.x] = sh[255];
}

__global__ void scan2_kernel(int* __restrict__ bsum, int nb) {
  __shared__ int sh[512];
  int t = threadIdx.x;
  int v = (t < nb) ? bsum[t] : 0;
  sh[t] = v;
  __syncthreads();
  for (int d = 1; d < 512; d <<= 1) {
    int x = (t >= (unsigned)d) ? sh[t - d] : 0;
    __syncthreads();
    sh[t] += x;
    __syncthreads();
  }
  if (t < nb) bsum[t] = sh[t] - v;
}

__global__ void scan3_kernel(int* __restrict__ off, const int* __restrict__ bsum, int n) {
  int idx = blockIdx.x * 256 + threadIdx.x;
  if (idx < n) off[idx] += bsum[blockIdx.x];
}

__global__ void scatter_kernel(const int* __restrict__ src, const int* __restrict__ dst,
                               const int* __restrict__ off, int* __restrict__ cursor,
                               int* __restrict__ csr, int E) {
  int e = blockIdx.x * 256 + threadIdx.x;
  if (e < E) {
    int d = dst[e];
    int p = off[d] + atomicAdd(&cursor[d], 1);
    csr[p] = src[e];
  }
}

// ---------------- weight packing: WT[512][128] bf16 = [Wq|Wk|Wv|Ws]^T ----------------

__global__ void pack_w_kernel(const float* __restrict__ Wq, const float* __restrict__ Wk,
                              const float* __restrict__ Wv, const float* __restrict__ Ws,
                              const float* __restrict__ bq, const float* __restrict__ bk,
                              const float* __restrict__ bv, const float* __restrict__ bs,
                              __hip_bfloat16* __restrict__ WT, float* __restrict__ bcat) {
  int idx = blockIdx.x * 256 + threadIdx.x;
  if (idx < 512 * DH) {
    int c = idx >> 7, k = idx & 127;
    int which = c >> 7, cc = c & 127;
    const float* W = (which == 0) ? Wq : (which == 1) ? Wk : (which == 2) ? Wv : Ws;
    WT[idx] = __float2bfloat16(W[k * DH + cc]);
    if (k == 0) {
      const float* b = (which == 0) ? bq : (which == 1) ? bk : (which == 2) ? bv : bs;
      bcat[c] = b[cc];
    }
  }
}

// ---------------- fused QKVS GEMM (bf16 MFMA) ----------------
// out = X[N,128] @ W[128,512] + b, scattered to:
//   q  bf16 [N][128]            (seg 0)
//   kvp bf16 [N][256] packed as {k0,k1,v0,v1} per feature pair  (segs 1,2)
//   xr fp32 [N][128]            (seg 3)
// Block: 256 thr = 4 waves; 64(m) x 64(n) tile; whole K=128 staged once in LDS.

__global__ __launch_bounds__(256)
void gemm_qkvs(const short* __restrict__ Xb, const short* __restrict__ WT,
               const float* __restrict__ bc, __hip_bfloat16* __restrict__ qout,
               __hip_bfloat16* __restrict__ kvp, float* __restrict__ xrout, int Nn) {
  __shared__ short As[64][136];   // +8 pad: frag-read bank stride 4 -> 2-way (free)
  __shared__ short Bs[64][136];
  const int row0 = blockIdx.x * 64;
  const int col0 = blockIdx.y * 64;
  const int tid = threadIdx.x;
  const int rsub = tid >> 4;
  const int koff = (tid & 15) * 8;

#pragma unroll
  for (int p = 0; p < 4; ++p) {
    int r = p * 16 + rsub;
    int row = row0 + r; if (row >= Nn) row = Nn - 1;
    *(int4*)&As[r][koff] = *(const int4*)&Xb[(size_t)row * 128 + koff];
    *(int4*)&Bs[r][koff] = *(const int4*)&WT[(size_t)(col0 + r) * 128 + koff];
  }
  __syncthreads();

  const int w = tid >> 6, lane = tid & 63, quad = lane >> 4, l16 = lane & 15;
  floatx4 acc[4];
#pragma unroll
  for (int nt = 0; nt < 4; ++nt) acc[nt] = (floatx4){0.f, 0.f, 0.f, 0.f};

#pragma unroll
  for (int kt = 0; kt < 4; ++kt) {
    short8 af = *(const short8*)&As[w * 16 + l16][kt * 32 + quad * 8];
#pragma unroll
    for (int nt = 0; nt < 4; ++nt) {
      short8 bf = *(const short8*)&Bs[nt * 16 + l16][kt * 32 + quad * 8];
      acc[nt] = __builtin_amdgcn_mfma_f32_16x16x32_bf16(af, bf, acc[nt], 0, 0, 0);
    }
  }

  const int seg = col0 >> 7;
#pragma unroll
  for (int nt = 0; nt < 4; ++nt) {
#pragma unroll
    for (int reg = 0; reg < 4; ++reg) {
      int grow = row0 + w * 16 + quad * 4 + reg;
      if (grow >= Nn) continue;
      int gcol = col0 + nt * 16 + l16;
      float v = acc[nt][reg] + bc[gcol];
      int cb = (col0 & 127) + nt * 16 + l16;
      if (seg == 0) {
        qout[(size_t)grow * 128 + cb] = __float2bfloat16(v);
      } else if (seg == 1) {
        kvp[(size_t)grow * 256 + ((cb >> 1) << 2) + (cb & 1)] = __float2bfloat16(v);
      } else if (seg == 2) {
        kvp[(size_t)grow * 256 + ((cb >> 1) << 2) + 2 + (cb & 1)] = __float2bfloat16(v);
      } else {
        xrout[(size_t)grow * 128 + cb] = v;
      }
    }
  }
}

// ---------------- attention: one WAVE per node ----------------
// lane l owns feature pair (2l, 2l+1); head = l>>4 (16-lane softmax groups).
// kvp packed {k0,k1,v0,v1} -> one dwordx2 gather per lane per edge.
// No max-subtraction (|alpha| << 88, shift-invariant). h written in place over q.

__global__ __launch_bounds__(256)
void attn_kernel(__hip_bfloat16* __restrict__ q_h, const __hip_bfloat16* __restrict__ kvp,
                 const float* __restrict__ xrbuf, const int* __restrict__ off,
                 const int* __restrict__ deg, const int* __restrict__ csr,
                 const float* __restrict__ Wb, int Nn) {
  int i = blockIdx.x * 4 + (threadIdx.x >> 6);
  if (i >= Nn) return;
  int l = threadIdx.x & 63;

  ushort2 qp = ((const ushort2*)q_h)[(size_t)i * 64 + l];
  float q0 = bfu2f(qp.x), q1 = bfu2f(qp.y);
  int e0 = off[i];
  int e1 = e0 + deg[i];

  float denA = 0.f, a0A = 0.f, a1A = 0.f;
  float denB = 0.f, a0B = 0.f, a1B = 0.f;

  auto body = [&](int e, float& den, float& a0, float& a1) {
    int s = csr[e];
    uint2 kq = ((const uint2*)kvp)[(size_t)s * 64 + l];
    float k0 = bfu2f(kq.x), k1 = bfh2f(kq.x);
    float v0 = bfu2f(kq.y), v1 = bfh2f(kq.y);
    float d = q0 * k0 + q1 * k1;
    d += __shfl_xor(d, 1);
    d += __shfl_xor(d, 2);
    d += __shfl_xor(d, 4);
    d += __shfl_xor(d, 8);
    float p = __expf(d * 0.17677669529663687f);   // 1/sqrt(32)
    den += p; a0 += p * v0; a1 += p * v1;
  };

  int e = e0;
  for (; e + 1 < e1; e += 2) {
    body(e, denA, a0A, a1A);
    body(e + 1, denB, a0B, a1B);
  }
  if (e < e1) body(e, denA, a0A, a1A);

  float denom = denA + denB + 1e-16f;
  float o0 = (a0A + a0B) / denom;
  float o1 = (a1A + a1B) / denom;

  float2 xp = ((const float2*)xrbuf)[(size_t)i * 64 + l];
  float xr0 = xp.x, xr1 = xp.y;

  // beta = sigmoid([out | xr | out-xr] . Wb), full 64-lane reduce
  float c = o0 * Wb[2 * l] + o1 * Wb[2 * l + 1]
          + xr0 * Wb[128 + 2 * l] + xr1 * Wb[128 + 2 * l + 1]
          + (o0 - xr0) * Wb[256 + 2 * l] + (o1 - xr1) * Wb[256 + 2 * l + 1];
  c += __shfl_xor(c, 1);
  c += __shfl_xor(c, 2);
  c += __shfl_xor(c, 4);
  c += __shfl_xor(c, 8);
  c += __shfl_xor(c, 16);
  c += __shfl_xor(c, 32);
  float beta = 1.f / (1.f + __expf(-c));
  float h0 = fmaxf(beta * xr0 + (1.f - beta) * o0, 0.f);
  float h1 = fmaxf(beta * xr1 + (1.f - beta) * o1, 0.f);
  ushort2 hw;
  hw.x = (unsigned short)(__bfloat16_as_ushort(__float2bfloat16(h0)));
  hw.y = (unsigned short)(__bfloat16_as_ushort(__float2bfloat16(h1)));
  ((ushort2*)q_h)[(size_t)i * 64 + l] = hw;
}

// ---------------- global mean pool (bf16 h) ----------------

__global__ void pool_kernel(const __hip_bfloat16* __restrict__ h, const int* __restrict__ batch,
                            float* __restrict__ gsum, float* __restrict__ gcnt, int Nn) {
  int idx = blockIdx.x * 256 + threadIdx.x;
  int n = idx >> 7;
  int f = idx & 127;
  if (n < Nn) {
    int g = batch[n];
    atomicAdd(&gsum[(size_t)g * DH + f], __bfloat162float(h[(size_t)n * DH + f]));
    if (f == 0) atomicAdd(&gcnt[g], 1.0f);
  }
}

// ---------------- MLP head ----------------

__global__ __launch_bounds__(128)
void mlp_kernel(const float* __restrict__ gsum, const float* __restrict__ gcnt,
                const float* __restrict__ W1, const float* __restrict__ b1,
                const float* __restrict__ W2, const float* __restrict__ b2,
                const float* __restrict__ W3, const float* __restrict__ b3,
                float* __restrict__ out) {
  int g = blockIdx.x;
  int t = threadIdx.x;
  __shared__ float gv[128];
  __shared__ float t1[64];
  __shared__ float t2[32];
  float cnt = fmaxf(gcnt[g], 1.0f);
  gv[t] = gsum[(size_t)g * DH + t] / cnt;
  __syncthreads();
  if (t < 64) {
    float s = b1[t];
    for (int k = 0; k < 128; ++k) s += gv[k] * W1[k * 64 + t];
    t1[t] = fmaxf(s, 0.f);
  }
  __syncthreads();
  if (t < 32) {
    float s = b2[t];
    for (int k = 0; k < 64; ++k) s += t1[k] * W2[k * 32 + t];
    t2[t] = fmaxf(s, 0.f);
  }
  __syncthreads();
  if (t == 0) {
    float s = b3[0];
    for (int k = 0; k < 32; ++k) s += t2[k] * W3[k];
    out[g] = 1.f / (1.f + __expf(-s));
  }
}

// ---------------- launch ----------------

extern "C" void kernel_launch(void* const* d_in, const int* in_sizes, int n_in,
                              void* d_out, int out_size, void* d_ws, size_t ws_size,
                              hipStream_t stream) {
  const float* x = (const float*)d_in[0];
  const int* edge_index = (const int*)d_in[1];
  const int* batch = (const int*)d_in[2];
  const int N = in_sizes[0] / DH;
  const int E = in_sizes[1] / 2;
  const int G = out_size;
  const int* src = edge_index;
  const int* dst = edge_index + E;

  const float* in_Wq = (const float*)d_in[3];
  const float* in_bq = (const float*)d_in[4];
  const float* in_Wk = (const float*)d_in[5];
  const float* in_bk = (const float*)d_in[6];
  const float* in_Wv = (const float*)d_in[7];
  const float* in_bv = (const float*)d_in[8];
  const float* in_Ws = (const float*)d_in[9];
  const float* in_bs = (const float*)d_in[10];
  const float* in_Wbeta = (const float*)d_in[11];
  const float* blk_Wq = (const float*)d_in[12];
  const float* blk_bq = (const float*)d_in[13];
  const float* blk_Wk = (const float*)d_in[14];
  const float* blk_bk = (const float*)d_in[15];
  const float* blk_Wv = (const float*)d_in[16];
  const float* blk_bv = (const float*)d_in[17];
  const float* blk_Ws = (const float*)d_in[18];
  const float* blk_bs = (const float*)d_in[19];
  const float* blk_Wbeta = (const float*)d_in[20];

  // workspace carve (256B aligned) — ~161 MB
  char* p = (char*)d_ws;
  auto take = [&](size_t bytes) { char* r = p; p += (bytes + 255) & ~(size_t)255; return r; };
  __hip_bfloat16* h0 = (__hip_bfloat16*)take((size_t)N * DH * 2);   // h / q ping
  __hip_bfloat16* h1 = (__hip_bfloat16*)take((size_t)N * DH * 2);   // h / q pong
  __hip_bfloat16* kvp = (__hip_bfloat16*)take((size_t)N * 256 * 2); // packed k/v pairs
  float* xr   = (float*)take((size_t)N * DH * 4);
  __hip_bfloat16* WT = (__hip_bfloat16*)take((size_t)512 * DH * 2);
  float* bcat = (float*)take(512 * 4);
  int*   deg  = (int*)take((size_t)N * 4);
  int*   off  = (int*)take((size_t)N * 4);
  int*   cursor = (int*)take((size_t)N * 4);
  int*   bsum = (int*)take(512 * 4);
  int*   csr  = (int*)take((size_t)E * 4);
  float* gsum = (float*)take((size_t)G * DH * 4);
  float* gcnt = (float*)take((size_t)G * 4);
  (void)n_in;
  if ((size_t)(p - (char*)d_ws) > ws_size) return;

  int eb = (E + 255) / 256;
  int nb = (N + 255) / 256;
  zero_i32<<<nb, 256, 0, stream>>>(deg, N);
  zero_i32<<<nb, 256, 0, stream>>>(cursor, N);
  zero_f32<<<(G * DH + 255) / 256, 256, 0, stream>>>(gsum, G * DH);
  zero_f32<<<(G + 255) / 256, 256, 0, stream>>>(gcnt, G);

  hist_kernel<<<eb, 256, 0, stream>>>(dst, deg, E);
  scan1_kernel<<<nb, 256, 0, stream>>>(deg, off, bsum, N);
  scan2_kernel<<<1, 512, 0, stream>>>(bsum, nb);
  scan3_kernel<<<nb, 256, 0, stream>>>(off, bsum, N);
  scatter_kernel<<<eb, 256, 0, stream>>>(src, dst, off, cursor, csr, E);

  cvt_bf16<<<(int)(((size_t)N * DH + 255) / 256), 256, 0, stream>>>(x, h0, N * DH);

  for (int l = 0; l < 4; ++l) {
    const float *Wq, *Wk, *Wv, *Ws, *bq, *bk, *bv, *bs, *Wb;
    if (l == 0) {
      Wq = in_Wq; Wk = in_Wk; Wv = in_Wv; Ws = in_Ws;
      bq = in_bq; bk = in_bk; bv = in_bv; bs = in_bs; Wb = in_Wbeta;
    } else {
      int m = l - 1;
      Wq = blk_Wq + (size_t)m * DH * DH; Wk = blk_Wk + (size_t)m * DH * DH;
      Wv = blk_Wv + (size_t)m * DH * DH; Ws = blk_Ws + (size_t)m * DH * DH;
      bq = blk_bq + (size_t)m * DH; bk = blk_bk + (size_t)m * DH;
      bv = blk_bv + (size_t)m * DH; bs = blk_bs + (size_t)m * DH;
      Wb = blk_Wbeta + (size_t)m * 3 * DH;
    }
    __hip_bfloat16* hin  = (l & 1) ? h1 : h0;
    __hip_bfloat16* qbuf = (l & 1) ? h0 : h1;
    pack_w_kernel<<<(512 * DH + 255) / 256, 256, 0, stream>>>(Wq, Wk, Wv, Ws, bq, bk, bv, bs, WT, bcat);
    dim3 gg((N + 63) / 64, 8);
    gemm_qkvs<<<gg, 256, 0, stream>>>((const short*)hin, (const short*)WT, bcat, qbuf, kvp, xr, N);
    attn_kernel<<<(N + 3) / 4, 256, 0, stream>>>(qbuf, kvp, xr, off, deg, csr, Wb, N);
  }

  // after 4 layers h lives in h0 (l=3 wrote qbuf=h0)
  pool_kernel<<<(int)(((size_t)N * DH + 255) / 256), 256, 0, stream>>>(h0, batch, gsum, gcnt, N);
  mlp_kernel<<<G, 128, 0, stream>>>(gsum, gcnt,
      (const float*)d_in[21], (const float*)d_in[22],
      (const float*)d_in[23], (const float*)d_in[24],
      (const float*)d_in[25], (const float*)d_in[26],
      (float*)d_out);
}

// Round 4
// 1102.473 us; speedup vs baseline: 1.9750x; 1.1617x over previous
//
#include <hip/hip_runtime.h>
#include <hip/hip_bf16.h>
#include <cstdint>

#define DH 128   // hidden dim

typedef __attribute__((ext_vector_type(8))) short short8;
typedef __attribute__((ext_vector_type(4))) float floatx4;
typedef __attribute__((ext_vector_type(2))) float floatx2;

__device__ __forceinline__ float bflo(unsigned u) { return __uint_as_float(u << 16); }
__device__ __forceinline__ float bfhi(unsigned u) { return __uint_as_float(u & 0xffff0000u); }

template<int CTRL>
__device__ __forceinline__ float dpp_add(float x) {
  int y = __builtin_amdgcn_update_dpp(0, __float_as_int(x), CTRL, 0xf, 0xf, true);
  return x + __int_as_float(y);
}

// ---------------- zero-fill ----------------

__global__ void zero_i32(int* __restrict__ p, int n) {
  int i = blockIdx.x * 256 + threadIdx.x;
  if (i < n) p[i] = 0;
}

// ---------------- fp32 -> bf16 convert ----------------

__global__ void cvt_bf16(const float* __restrict__ x, __hip_bfloat16* __restrict__ o, int n) {
  int i = blockIdx.x * 256 + threadIdx.x;
  if (i < n) o[i] = __float2bfloat16(x[i]);
}

// ---------------- CSR build (also reused for graph segments) ----------------

__global__ void hist_kernel(const int* __restrict__ dst, int* __restrict__ deg, int E) {
  int e = blockIdx.x * 256 + threadIdx.x;
  if (e < E) atomicAdd(&deg[dst[e]], 1);
}

__global__ void scan1_kernel(const int* __restrict__ deg, int* __restrict__ off,
                             int* __restrict__ bsum, int n) {
  __shared__ int sh[256];
  int idx = blockIdx.x * 256 + threadIdx.x;
  int v = (idx < n) ? deg[idx] : 0;
  sh[threadIdx.x] = v;
  __syncthreads();
  for (int d = 1; d < 256; d <<= 1) {
    int x = (threadIdx.x >= (unsigned)d) ? sh[threadIdx.x - d] : 0;
    __syncthreads();
    sh[threadIdx.x] += x;
    __syncthreads();
  }
  if (idx < n) off[idx] = sh[threadIdx.x] - v;   // exclusive
  if (threadIdx.x == 255) bsum[blockIdx.x] = sh[255];
}

__global__ void scan2_kernel(int* __restrict__ bsum, int nb) {
  __shared__ int sh[512];
  int t = threadIdx.x;
  int v = (t < nb) ? bsum[t] : 0;
  sh[t] = v;
  __syncthreads();
  for (int d = 1; d < 512; d <<= 1) {
    int x = (t >= (unsigned)d) ? sh[t - d] : 0;
    __syncthreads();
    sh[t] += x;
    __syncthreads();
  }
  if (t < nb) bsum[t] = sh[t] - v;
}

__global__ void scan3_kernel(int* __restrict__ off, const int* __restrict__ bsum, int n) {
  int idx = blockIdx.x * 256 + threadIdx.x;
  if (idx < n) off[idx] += bsum[blockIdx.x];
}

__global__ void scatter_kernel(const int* __restrict__ src, const int* __restrict__ dst,
                               const int* __restrict__ off, int* __restrict__ cursor,
                               int* __restrict__ csr, int E) {
  int e = blockIdx.x * 256 + threadIdx.x;
  if (e < E) {
    int d = dst[e];
    int p = off[d] + atomicAdd(&cursor[d], 1);
    csr[p] = src[e];
  }
}

// ---------------- weight packing: WT[512][128] bf16 = [Wq|Wk|Wv|Ws]^T ----------------

__global__ void pack_w_kernel(const float* __restrict__ Wq, const float* __restrict__ Wk,
                              const float* __restrict__ Wv, const float* __restrict__ Ws,
                              const float* __restrict__ bq, const float* __restrict__ bk,
                              const float* __restrict__ bv, const float* __restrict__ bs,
                              __hip_bfloat16* __restrict__ WT, float* __restrict__ bcat) {
  int idx = blockIdx.x * 256 + threadIdx.x;
  if (idx < 512 * DH) {
    int c = idx >> 7, k = idx & 127;
    int which = c >> 7, cc = c & 127;
    const float* W = (which == 0) ? Wq : (which == 1) ? Wk : (which == 2) ? Wv : Ws;
    WT[idx] = __float2bfloat16(W[k * DH + cc]);
    if (k == 0) {
      const float* b = (which == 0) ? bq : (which == 1) ? bk : (which == 2) ? bv : bs;
      bcat[c] = b[cc];
    }
  }
}

// ---------------- fused QKVS GEMM (bf16 MFMA, one block = 64 rows x ALL 512 cols) --
// outputs: q bf16 [N][128], kvp fp8 [N][256] packed {k0,k1,v0,v1}/pair, xr bf16 [N][128]
// A staged to LDS once; B-frags read direct from global (WT 128KB, L2-resident).
// wave w handles col-tiles ct = {w, w+4}.

__global__ __launch_bounds__(256)
void gemm_qkvs(const short* __restrict__ Xb, const short* __restrict__ WT,
               const float* __restrict__ bc,
               unsigned short* __restrict__ qout,
               unsigned char* __restrict__ kvp,
               unsigned short* __restrict__ xrout, int Nn) {
  __shared__ short As[64][136];
  const int row0 = blockIdx.x * 64;
  const int tid = threadIdx.x;
  {
    const int rsub = tid >> 4;
    const int koff = (tid & 15) * 8;
#pragma unroll
    for (int p = 0; p < 4; ++p) {
      int r = p * 16 + rsub;
      int row = row0 + r; if (row >= Nn) row = Nn - 1;
      *(int4*)&As[r][koff] = *(const int4*)&Xb[(size_t)row * 128 + koff];
    }
  }
  __syncthreads();

  const int w = tid >> 6, lane = tid & 63, quad = lane >> 4, l16 = lane & 15;

  short8 af[4][4];
#pragma unroll
  for (int mt = 0; mt < 4; ++mt)
#pragma unroll
    for (int kt = 0; kt < 4; ++kt)
      af[mt][kt] = *(const short8*)&As[mt * 16 + l16][kt * 32 + quad * 8];

#pragma unroll
  for (int cti = 0; cti < 2; ++cti) {
    const int ct = w + cti * 4;            // 0..7
    const int col0 = ct * 64;
    const int seg = ct >> 1;               // 0=q 1=k 2=v 3=xr
    const int cbase = (ct & 1) * 64;
#pragma unroll
    for (int nt = 0; nt < 4; ++nt) {
      const int gcol = col0 + nt * 16 + l16;
      short8 bf[4];
#pragma unroll
      for (int kt = 0; kt < 4; ++kt)
        bf[kt] = *(const short8*)&WT[(size_t)gcol * 128 + kt * 32 + quad * 8];
      float bias = bc[gcol];
      const int cb = cbase + nt * 16 + l16;   // 0..127 within segment
#pragma unroll
      for (int mt = 0; mt < 4; ++mt) {
        floatx4 acc = (floatx4){0.f, 0.f, 0.f, 0.f};
#pragma unroll
        for (int kt = 0; kt < 4; ++kt)
          acc = __builtin_amdgcn_mfma_f32_16x16x32_bf16(af[mt][kt], bf[kt], acc, 0, 0, 0);
#pragma unroll
        for (int reg = 0; reg < 4; ++reg) {
          int row = row0 + mt * 16 + quad * 4 + reg;
          if (row >= Nn) continue;
          float v = acc[reg] + bias;
          if (seg == 0) {
            qout[(size_t)row * 128 + cb] = __bfloat16_as_ushort(__float2bfloat16(v));
          } else if (seg == 1) {
            int b8 = __builtin_amdgcn_cvt_pk_fp8_f32(v, v, 0, false);
            kvp[(size_t)row * 256 + ((cb >> 1) << 2) + (cb & 1)] = (unsigned char)(b8 & 0xff);
          } else if (seg == 2) {
            int b8 = __builtin_amdgcn_cvt_pk_fp8_f32(v, v, 0, false);
            kvp[(size_t)row * 256 + ((cb >> 1) << 2) + 2 + (cb & 1)] = (unsigned char)(b8 & 0xff);
          } else {
            xrout[(size_t)row * 128 + cb] = __bfloat16_as_ushort(__float2bfloat16(v));
          }
        }
      }
    }
  }
}

// ---------------- attention: one WAVE per node, fp8 k/v, DPP softmax reduce ------
// lane l owns feature pair (2l,2l+1); head = l>>4 (16-lane DPP rows).
// per edge: 1 dword gather -> 2 cvt_pk -> dot -> 4 dpp-adds -> exp -> 3 acc.

__global__ __launch_bounds__(256)
void attn_kernel(unsigned int* __restrict__ q_h, const unsigned int* __restrict__ kvp,
                 const unsigned int* __restrict__ xrb, const int* __restrict__ off,
                 const int* __restrict__ deg, const int* __restrict__ csr,
                 const float* __restrict__ Wb, int Nn) {
  int i = blockIdx.x * 4 + (threadIdx.x >> 6);
  if (i >= Nn) return;
  int l = threadIdx.x & 63;

  unsigned qp = q_h[(size_t)i * 64 + l];
  float q0 = bflo(qp), q1 = bfhi(qp);
  int e0 = off[i], e1 = e0 + deg[i];

  float denA = 0.f, a0A = 0.f, a1A = 0.f;
  float denB = 0.f, a0B = 0.f, a1B = 0.f;

  auto body = [&](int e, float& den, float& a0, float& a1) {
    int s = csr[e];
    int kq = (int)kvp[(size_t)s * 64 + l];
    floatx2 kk = __builtin_amdgcn_cvt_pk_f32_fp8(kq, false);   // bytes 0,1 = k0,k1
    floatx2 vv = __builtin_amdgcn_cvt_pk_f32_fp8(kq, true);    // bytes 2,3 = v0,v1
    float d = q0 * kk.x + q1 * kk.y;
    d = dpp_add<0x128>(d);   // row_ror:8
    d = dpp_add<0x124>(d);   // row_ror:4
    d = dpp_add<0x122>(d);   // row_ror:2
    d = dpp_add<0x121>(d);   // row_ror:1
    float p = __expf(d * 0.17677669529663687f);   // 1/sqrt(32)
    den += p; a0 += p * vv.x; a1 += p * vv.y;
  };

  int e = e0;
  for (; e + 1 < e1; e += 2) { body(e, denA, a0A, a1A); body(e + 1, denB, a0B, a1B); }
  if (e < e1) body(e, denA, a0A, a1A);

  float denom = denA + denB + 1e-16f;
  float o0 = (a0A + a0B) / denom;
  float o1 = (a1A + a1B) / denom;

  unsigned xp = xrb[(size_t)i * 64 + l];
  float xr0 = bflo(xp), xr1 = bfhi(xp);

  float c = o0 * Wb[2 * l] + o1 * Wb[2 * l + 1]
          + xr0 * Wb[128 + 2 * l] + xr1 * Wb[128 + 2 * l + 1]
          + (o0 - xr0) * Wb[256 + 2 * l] + (o1 - xr1) * Wb[256 + 2 * l + 1];
  c += __shfl_xor(c, 1);
  c += __shfl_xor(c, 2);
  c += __shfl_xor(c, 4);
  c += __shfl_xor(c, 8);
  c += __shfl_xor(c, 16);
  c += __shfl_xor(c, 32);
  float beta = 1.f / (1.f + __expf(-c));
  float h0 = fmaxf(beta * xr0 + (1.f - beta) * o0, 0.f);
  float h1 = fmaxf(beta * xr1 + (1.f - beta) * o1, 0.f);
  unsigned hw = ((unsigned)__bfloat16_as_ushort(__float2bfloat16(h1)) << 16)
              | (unsigned)__bfloat16_as_ushort(__float2bfloat16(h0));
  q_h[(size_t)i * 64 + l] = hw;
}

// ---------------- fused mean-pool + MLP: one block (128 thr) per graph ----------

__global__ __launch_bounds__(128)
void poolmlp_kernel(const unsigned short* __restrict__ h, const int* __restrict__ goff,
                    const int* __restrict__ gdeg,
                    const float* __restrict__ W1, const float* __restrict__ b1,
                    const float* __restrict__ W2, const float* __restrict__ b2,
                    const float* __restrict__ W3, const float* __restrict__ b3,
                    float* __restrict__ out) {
  int g = blockIdx.x;
  int t = threadIdx.x;
  int n0 = goff[g], cnt = gdeg[g];
  float s = 0.f;
  for (int n = n0; n < n0 + cnt; ++n) s += bflo(h[(size_t)n * 128 + t]);
  __shared__ float gv[128];
  __shared__ float t1[64];
  __shared__ float t2[32];
  gv[t] = s / fmaxf((float)cnt, 1.0f);
  __syncthreads();
  if (t < 64) {
    float a = b1[t];
    for (int k = 0; k < 128; ++k) a += gv[k] * W1[k * 64 + t];
    t1[t] = fmaxf(a, 0.f);
  }
  __syncthreads();
  if (t < 32) {
    float a = b2[t];
    for (int k = 0; k < 64; ++k) a += t1[k] * W2[k * 32 + t];
    t2[t] = fmaxf(a, 0.f);
  }
  __syncthreads();
  if (t == 0) {
    float a = b3[0];
    for (int k = 0; k < 32; ++k) a += t2[k] * W3[k];
    out[g] = 1.f / (1.f + __expf(-a));
  }
}

// ---------------- launch ----------------

extern "C" void kernel_launch(void* const* d_in, const int* in_sizes, int n_in,
                              void* d_out, int out_size, void* d_ws, size_t ws_size,
                              hipStream_t stream) {
  const float* x = (const float*)d_in[0];
  const int* edge_index = (const int*)d_in[1];
  const int* batch = (const int*)d_in[2];
  const int N = in_sizes[0] / DH;
  const int E = in_sizes[1] / 2;
  const int G = out_size;
  const int* src = edge_index;
  const int* dst = edge_index + E;

  const float* in_Wq = (const float*)d_in[3];
  const float* in_bq = (const float*)d_in[4];
  const float* in_Wk = (const float*)d_in[5];
  const float* in_bk = (const float*)d_in[6];
  const float* in_Wv = (const float*)d_in[7];
  const float* in_bv = (const float*)d_in[8];
  const float* in_Ws = (const float*)d_in[9];
  const float* in_bs = (const float*)d_in[10];
  const float* in_Wbeta = (const float*)d_in[11];
  const float* blk_Wq = (const float*)d_in[12];
  const float* blk_bq = (const float*)d_in[13];
  const float* blk_Wk = (const float*)d_in[14];
  const float* blk_bk = (const float*)d_in[15];
  const float* blk_Wv = (const float*)d_in[16];
  const float* blk_bv = (const float*)d_in[17];
  const float* blk_Ws = (const float*)d_in[18];
  const float* blk_bs = (const float*)d_in[19];
  const float* blk_Wbeta = (const float*)d_in[20];

  // workspace carve (256B aligned) — ~135 MB
  char* p = (char*)d_ws;
  auto take = [&](size_t bytes) { char* r = p; p += (bytes + 255) & ~(size_t)255; return r; };
  __hip_bfloat16* h0 = (__hip_bfloat16*)take((size_t)N * DH * 2);
  __hip_bfloat16* h1 = (__hip_bfloat16*)take((size_t)N * DH * 2);
  unsigned char* kvp = (unsigned char*)take((size_t)N * 256);
  unsigned short* xr = (unsigned short*)take((size_t)N * DH * 2);
  __hip_bfloat16* WT = (__hip_bfloat16*)take((size_t)512 * DH * 2);
  float* bcat = (float*)take(512 * 4);
  int* deg    = (int*)take((size_t)N * 4);
  int* off    = (int*)take((size_t)N * 4);
  int* cursor = (int*)take((size_t)N * 4);
  int* bsum   = (int*)take(512 * 4);
  int* bsum2  = (int*)take(512 * 4);
  int* csr    = (int*)take((size_t)E * 4);
  int* gdeg   = (int*)take((size_t)G * 4);
  int* goff   = (int*)take((size_t)G * 4);
  (void)n_in;
  if ((size_t)(p - (char*)d_ws) > ws_size) return;

  int eb = (E + 255) / 256;
  int nb = (N + 255) / 256;
  int gb = (G + 255) / 256;
  zero_i32<<<nb, 256, 0, stream>>>(deg, N);
  zero_i32<<<nb, 256, 0, stream>>>(cursor, N);
  zero_i32<<<gb, 256, 0, stream>>>(gdeg, G);

  // edge CSR (by dst)
  hist_kernel<<<eb, 256, 0, stream>>>(dst, deg, E);
  scan1_kernel<<<nb, 256, 0, stream>>>(deg, off, bsum, N);
  scan2_kernel<<<1, 512, 0, stream>>>(bsum, nb);
  scan3_kernel<<<nb, 256, 0, stream>>>(off, bsum, N);
  scatter_kernel<<<eb, 256, 0, stream>>>(src, dst, off, cursor, csr, E);

  // graph segments (batch is sorted)
  hist_kernel<<<nb, 256, 0, stream>>>(batch, gdeg, N);
  scan1_kernel<<<gb, 256, 0, stream>>>(gdeg, goff, bsum2, G);
  scan2_kernel<<<1, 512, 0, stream>>>(bsum2, gb);
  scan3_kernel<<<gb, 256, 0, stream>>>(goff, bsum2, G);

  cvt_bf16<<<(int)(((size_t)N * DH + 255) / 256), 256, 0, stream>>>(x, h0, N * DH);

  for (int l = 0; l < 4; ++l) {
    const float *Wq, *Wk, *Wv, *Ws, *bq, *bk, *bv, *bs, *Wb;
    if (l == 0) {
      Wq = in_Wq; Wk = in_Wk; Wv = in_Wv; Ws = in_Ws;
      bq = in_bq; bk = in_bk; bv = in_bv; bs = in_bs; Wb = in_Wbeta;
    } else {
      int m = l - 1;
      Wq = blk_Wq + (size_t)m * DH * DH; Wk = blk_Wk + (size_t)m * DH * DH;
      Wv = blk_Wv + (size_t)m * DH * DH; Ws = blk_Ws + (size_t)m * DH * DH;
      bq = blk_bq + (size_t)m * DH; bk = blk_bk + (size_t)m * DH;
      bv = blk_bv + (size_t)m * DH; bs = blk_bs + (size_t)m * DH;
      Wb = blk_Wbeta + (size_t)m * 3 * DH;
    }
    __hip_bfloat16* hin  = (l & 1) ? h1 : h0;
    __hip_bfloat16* qbuf = (l & 1) ? h0 : h1;
    pack_w_kernel<<<(512 * DH + 255) / 256, 256, 0, stream>>>(Wq, Wk, Wv, Ws, bq, bk, bv, bs, WT, bcat);
    gemm_qkvs<<<(N + 63) / 64, 256, 0, stream>>>((const short*)hin, (const short*)WT, bcat,
        (unsigned short*)qbuf, kvp, xr, N);
    attn_kernel<<<(N + 3) / 4, 256, 0, stream>>>((unsigned int*)qbuf, (const unsigned int*)kvp,
        (const unsigned int*)xr, off, deg, csr, Wb, N);
  }

  // after 4 layers h lives in h0
  poolmlp_kernel<<<G, 128, 0, stream>>>((const unsigned short*)h0, goff, gdeg,
      (const float*)d_in[21], (const float*)d_in[22],
      (const float*)d_in[23], (const float*)d_in[24],
      (const float*)d_in[25], (const float*)d_in[26],
      (float*)d_out);
}

// Round 5
// 849.499 us; speedup vs baseline: 2.5631x; 1.2978x over previous
//
#include <hip/hip_runtime.h>
#include <hip/hip_bf16.h>
#include <cstdint>

#define DH 128   // hidden dim
#define NB 256   // partition blocks for CSR build
#define NBK 1024 // max buckets (N <= 131072)

typedef __attribute__((ext_vector_type(8))) short short8;
typedef __attribute__((ext_vector_type(4))) float floatx4;
typedef __attribute__((ext_vector_type(2))) float floatx2;

__device__ __forceinline__ float bflo(unsigned u) { return __uint_as_float(u << 16); }
__device__ __forceinline__ float bfhi(unsigned u) { return __uint_as_float(u & 0xffff0000u); }

template<int CTRL>
__device__ __forceinline__ float dpp_add(float x) {
  int y = __builtin_amdgcn_update_dpp(0, __float_as_int(x), CTRL, 0xf, 0xf, true);
  return x + __int_as_float(y);
}

// ---------------- zero-fill ----------------

__global__ void zero_i32(int* __restrict__ p, int n) {
  int i = blockIdx.x * 256 + threadIdx.x;
  if (i < n) p[i] = 0;
}

// ---------------- fp32 -> bf16 convert ----------------

__global__ void cvt_bf16(const float* __restrict__ x, __hip_bfloat16* __restrict__ o, int n) {
  int i = blockIdx.x * 256 + threadIdx.x;
  if (i < n) o[i] = __float2bfloat16(x[i]);
}

// ---------------- scans (generic, reused) ----------------

__global__ void hist_kernel(const int* __restrict__ dst, int* __restrict__ deg, int E) {
  int e = blockIdx.x * 256 + threadIdx.x;
  if (e < E) atomicAdd(&deg[dst[e]], 1);
}

__global__ void scan1_kernel(const int* __restrict__ deg, int* __restrict__ off,
                             int* __restrict__ bsum, int n) {
  __shared__ int sh[256];
  int idx = blockIdx.x * 256 + threadIdx.x;
  int v = (idx < n) ? deg[idx] : 0;
  sh[threadIdx.x] = v;
  __syncthreads();
  for (int d = 1; d < 256; d <<= 1) {
    int x = (threadIdx.x >= (unsigned)d) ? sh[threadIdx.x - d] : 0;
    __syncthreads();
    sh[threadIdx.x] += x;
    __syncthreads();
  }
  if (idx < n) off[idx] = sh[threadIdx.x] - v;   // exclusive
  if (threadIdx.x == 255) bsum[blockIdx.x] = sh[255];
}

__global__ void scan2_kernel(int* __restrict__ bsum, int nb) {
  __shared__ int sh[512];
  int t = threadIdx.x;
  int v = (t < nb) ? bsum[t] : 0;
  sh[t] = v;
  __syncthreads();
  for (int d = 1; d < 512; d <<= 1) {
    int x = (t >= (unsigned)d) ? sh[t - d] : 0;
    __syncthreads();
    sh[t] += x;
    __syncthreads();
  }
  if (t < nb) bsum[t] = sh[t] - v;
}

__global__ void scan3_kernel(int* __restrict__ off, const int* __restrict__ bsum, int n) {
  int idx = blockIdx.x * 256 + threadIdx.x;
  if (idx < n) off[idx] += bsum[blockIdx.x];
}

// ---------------- atomic-free CSR build (counting sort by dst>>7) ----------------
// phase 1: per-block LDS bucket histograms -> hist[blk*NBK + b]

__global__ __launch_bounds__(256)
void csr_p1(const int* __restrict__ dst, int* __restrict__ hist, int E, int chunk) {
  __shared__ int cnt[NBK];
  const int blk = blockIdx.x, tid = threadIdx.x;
  for (int c = tid; c < NBK; c += 256) cnt[c] = 0;
  __syncthreads();
  int base = blk * chunk;
  int end = base + chunk; if (end > E) end = E;
  for (int e = base + tid; e < end; e += 256) atomicAdd(&cnt[dst[e] >> 7], 1);
  __syncthreads();
  for (int c = tid; c < NBK; c += 256) hist[blk * NBK + c] = cnt[c];
}

// phase 2: per-bucket exclusive prefix over blocks (in place) + bucket totals

__global__ __launch_bounds__(256)
void csr_p2(int* __restrict__ hist, int* __restrict__ total) {
  int b = blockIdx.x * 256 + threadIdx.x;   // bucket id, 0..NBK-1
  int run = 0;
  for (int blk = 0; blk < NB; ++blk) {
    int v = hist[blk * NBK + b];
    hist[blk * NBK + b] = run;
    run += v;
  }
  total[b] = run;
}

// phase 3: partition edges into bucket-grouped array, packed (src<<7)|(dst&127)

__global__ __launch_bounds__(256)
void csr_p3(const int* __restrict__ src, const int* __restrict__ dst,
            const int* __restrict__ hist, const int* __restrict__ tstart,
            int* __restrict__ part, int E, int chunk) {
  __shared__ int cur[NBK];
  const int blk = blockIdx.x, tid = threadIdx.x;
  for (int c = tid; c < NBK; c += 256) cur[c] = hist[blk * NBK + c] + tstart[c];
  __syncthreads();
  int base = blk * chunk;
  int end = base + chunk; if (end > E) end = E;
  for (int e = base + tid; e < end; e += 256) {
    int d = dst[e];
    int b = d >> 7;
    int pos = atomicAdd(&cur[b], 1);     // LDS atomic
    part[pos] = (src[e] << 7) | (d & 127);
  }
}

// phase 4: one block per bucket -> deg, off, csr (all writes local/sequential)

__global__ __launch_bounds__(256)
void csr_p4(const int* __restrict__ part, const int* __restrict__ tstart,
            const int* __restrict__ total, int* __restrict__ deg,
            int* __restrict__ off, int* __restrict__ csr, int Nn) {
  __shared__ int lcnt[128], lscan[128], lcur[128];
  const int b = blockIdx.x, tid = threadIdx.x;
  const int p0 = tstart[b];
  const int m = total[b];
  if (tid < 128) lcnt[tid] = 0;
  __syncthreads();
  for (int k = tid; k < m; k += 256) atomicAdd(&lcnt[part[p0 + k] & 127], 1);
  __syncthreads();
  if (tid < 128) lscan[tid] = lcnt[tid];
  __syncthreads();
  for (int d = 1; d < 128; d <<= 1) {
    int v = 0;
    if (tid < 128 && tid >= d) v = lscan[tid - d];
    __syncthreads();
    if (tid < 128) lscan[tid] += v;
    __syncthreads();
  }
  if (tid < 128) {
    int ex = lscan[tid] - lcnt[tid];
    lcur[tid] = ex;
    int n = (b << 7) + tid;
    if (n < Nn) { deg[n] = lcnt[tid]; off[n] = p0 + ex; }
  }
  __syncthreads();
  for (int k = tid; k < m; k += 256) {
    int pk = part[p0 + k];
    int pos = p0 + atomicAdd(&lcur[pk & 127], 1);   // LDS atomic
    csr[pos] = pk >> 7;
  }
}

// ---------------- weight packing: WT[512][128] bf16 = [Wq|Wk|Wv|Ws]^T ----------------

__global__ void pack_w_kernel(const float* __restrict__ Wq, const float* __restrict__ Wk,
                              const float* __restrict__ Wv, const float* __restrict__ Ws,
                              const float* __restrict__ bq, const float* __restrict__ bk,
                              const float* __restrict__ bv, const float* __restrict__ bs,
                              __hip_bfloat16* __restrict__ WT, float* __restrict__ bcat) {
  int idx = blockIdx.x * 256 + threadIdx.x;
  if (idx < 512 * DH) {
    int c = idx >> 7, k = idx & 127;
    int which = c >> 7, cc = c & 127;
    const float* W = (which == 0) ? Wq : (which == 1) ? Wk : (which == 2) ? Wv : Ws;
    WT[idx] = __float2bfloat16(W[k * DH + cc]);
    if (k == 0) {
      const float* b = (which == 0) ? bq : (which == 1) ? bk : (which == 2) ? bv : bs;
      bcat[c] = b[cc];
    }
  }
}

// ---------------- fused QKVS GEMM (bf16 MFMA, one block = 64 rows x ALL 512 cols) --

__global__ __launch_bounds__(256)
void gemm_qkvs(const short* __restrict__ Xb, const short* __restrict__ WT,
               const float* __restrict__ bc,
               unsigned short* __restrict__ qout,
               unsigned char* __restrict__ kvp,
               unsigned short* __restrict__ xrout, int Nn) {
  __shared__ short As[64][136];
  const int row0 = blockIdx.x * 64;
  const int tid = threadIdx.x;
  {
    const int rsub = tid >> 4;
    const int koff = (tid & 15) * 8;
#pragma unroll
    for (int p = 0; p < 4; ++p) {
      int r = p * 16 + rsub;
      int row = row0 + r; if (row >= Nn) row = Nn - 1;
      *(int4*)&As[r][koff] = *(const int4*)&Xb[(size_t)row * 128 + koff];
    }
  }
  __syncthreads();

  const int w = tid >> 6, lane = tid & 63, quad = lane >> 4, l16 = lane & 15;

  short8 af[4][4];
#pragma unroll
  for (int mt = 0; mt < 4; ++mt)
#pragma unroll
    for (int kt = 0; kt < 4; ++kt)
      af[mt][kt] = *(const short8*)&As[mt * 16 + l16][kt * 32 + quad * 8];

#pragma unroll
  for (int cti = 0; cti < 2; ++cti) {
    const int ct = w + cti * 4;            // 0..7
    const int col0 = ct * 64;
    const int seg = ct >> 1;               // 0=q 1=k 2=v 3=xr
    const int cbase = (ct & 1) * 64;
#pragma unroll
    for (int nt = 0; nt < 4; ++nt) {
      const int gcol = col0 + nt * 16 + l16;
      short8 bf[4];
#pragma unroll
      for (int kt = 0; kt < 4; ++kt)
        bf[kt] = *(const short8*)&WT[(size_t)gcol * 128 + kt * 32 + quad * 8];
      float bias = bc[gcol];
      const int cb = cbase + nt * 16 + l16;   // 0..127 within segment
#pragma unroll
      for (int mt = 0; mt < 4; ++mt) {
        floatx4 acc = (floatx4){0.f, 0.f, 0.f, 0.f};
#pragma unroll
        for (int kt = 0; kt < 4; ++kt)
          acc = __builtin_amdgcn_mfma_f32_16x16x32_bf16(af[mt][kt], bf[kt], acc, 0, 0, 0);
#pragma unroll
        for (int reg = 0; reg < 4; ++reg) {
          int row = row0 + mt * 16 + quad * 4 + reg;
          if (row >= Nn) continue;
          float v = acc[reg] + bias;
          if (seg == 0) {
            qout[(size_t)row * 128 + cb] = __bfloat16_as_ushort(__float2bfloat16(v));
          } else if (seg == 1) {
            int b8 = __builtin_amdgcn_cvt_pk_fp8_f32(v, v, 0, false);
            kvp[(size_t)row * 256 + ((cb >> 1) << 2) + (cb & 1)] = (unsigned char)(b8 & 0xff);
          } else if (seg == 2) {
            int b8 = __builtin_amdgcn_cvt_pk_fp8_f32(v, v, 0, false);
            kvp[(size_t)row * 256 + ((cb >> 1) << 2) + 2 + (cb & 1)] = (unsigned char)(b8 & 0xff);
          } else {
            xrout[(size_t)row * 128 + cb] = __bfloat16_as_ushort(__float2bfloat16(v));
          }
        }
      }
    }
  }
}

// ---------------- attention: one WAVE per node, scalarized edge loop ------------
// wave id forced uniform via readfirstlane -> off/deg/csr become s_loads, loop
// control in SALU, kvp gather = saddr + (lane*4). 4 independent accumulator chains.

__global__ __launch_bounds__(256)
void attn_kernel(unsigned int* __restrict__ q_h, const unsigned int* __restrict__ kvp,
                 const unsigned int* __restrict__ xrb, const int* __restrict__ off,
                 const int* __restrict__ deg, const int* __restrict__ csr,
                 const float* __restrict__ Wb, int Nn) {
  int wv = __builtin_amdgcn_readfirstlane(threadIdx.x >> 6);
  int i = blockIdx.x * 4 + wv;
  if (i >= Nn) return;
  int l = threadIdx.x & 63;

  unsigned qp = q_h[(size_t)i * 64 + l];
  float q0 = bflo(qp), q1 = bfhi(qp);
  int e0 = off[i], e1 = e0 + deg[i];

  float den0 = 0.f, x00 = 0.f, x10 = 0.f;
  float den1 = 0.f, x01 = 0.f, x11 = 0.f;
  float den2 = 0.f, x02 = 0.f, x12 = 0.f;
  float den3 = 0.f, x03 = 0.f, x13 = 0.f;

  auto body = [&](int e, float& den, float& a0, float& a1) {
    int s = csr[e];
    int kq = (int)kvp[(size_t)s * 64 + l];
    floatx2 kk = __builtin_amdgcn_cvt_pk_f32_fp8(kq, false);   // bytes 0,1 = k0,k1
    floatx2 vv = __builtin_amdgcn_cvt_pk_f32_fp8(kq, true);    // bytes 2,3 = v0,v1
    float d = q0 * kk.x + q1 * kk.y;
    d = dpp_add<0x128>(d);   // row_ror:8
    d = dpp_add<0x124>(d);   // row_ror:4
    d = dpp_add<0x122>(d);   // row_ror:2
    d = dpp_add<0x121>(d);   // row_ror:1
    float p = __expf(d * 0.17677669529663687f);   // 1/sqrt(32)
    den += p; a0 += p * vv.x; a1 += p * vv.y;
  };

  int e = e0;
  for (; e + 3 < e1; e += 4) {
    body(e + 0, den0, x00, x10);
    body(e + 1, den1, x01, x11);
    body(e + 2, den2, x02, x12);
    body(e + 3, den3, x03, x13);
  }
  for (; e < e1; ++e) body(e, den0, x00, x10);

  float denom = den0 + den1 + den2 + den3 + 1e-16f;
  float o0 = (x00 + x01 + x02 + x03) / denom;
  float o1 = (x10 + x11 + x12 + x13) / denom;

  unsigned xp = xrb[(size_t)i * 64 + l];
  float xr0 = bflo(xp), xr1 = bfhi(xp);

  float c = o0 * Wb[2 * l] + o1 * Wb[2 * l + 1]
          + xr0 * Wb[128 + 2 * l] + xr1 * Wb[128 + 2 * l + 1]
          + (o0 - xr0) * Wb[256 + 2 * l] + (o1 - xr1) * Wb[256 + 2 * l + 1];
  c += __shfl_xor(c, 1);
  c += __shfl_xor(c, 2);
  c += __shfl_xor(c, 4);
  c += __shfl_xor(c, 8);
  c += __shfl_xor(c, 16);
  c += __shfl_xor(c, 32);
  float beta = 1.f / (1.f + __expf(-c));
  float h0 = fmaxf(beta * xr0 + (1.f - beta) * o0, 0.f);
  float h1 = fmaxf(beta * xr1 + (1.f - beta) * o1, 0.f);
  unsigned hw = ((unsigned)__bfloat16_as_ushort(__float2bfloat16(h1)) << 16)
              | (unsigned)__bfloat16_as_ushort(__float2bfloat16(h0));
  q_h[(size_t)i * 64 + l] = hw;
}

// ---------------- fused mean-pool + MLP ----------------

__global__ __launch_bounds__(128)
void poolmlp_kernel(const unsigned short* __restrict__ h, const int* __restrict__ goff,
                    const int* __restrict__ gdeg,
                    const float* __restrict__ W1, const float* __restrict__ b1,
                    const float* __restrict__ W2, const float* __restrict__ b2,
                    const float* __restrict__ W3, const float* __restrict__ b3,
                    float* __restrict__ out) {
  int g = blockIdx.x;
  int t = threadIdx.x;
  int n0 = goff[g], cnt = gdeg[g];
  float s = 0.f;
  for (int n = n0; n < n0 + cnt; ++n) s += bflo(h[(size_t)n * 128 + t]);
  __shared__ float gv[128];
  __shared__ float t1[64];
  __shared__ float t2[32];
  gv[t] = s / fmaxf((float)cnt, 1.0f);
  __syncthreads();
  if (t < 64) {
    float a = b1[t];
    for (int k = 0; k < 128; ++k) a += gv[k] * W1[k * 64 + t];
    t1[t] = fmaxf(a, 0.f);
  }
  __syncthreads();
  if (t < 32) {
    float a = b2[t];
    for (int k = 0; k < 64; ++k) a += t1[k] * W2[k * 32 + t];
    t2[t] = fmaxf(a, 0.f);
  }
  __syncthreads();
  if (t == 0) {
    float a = b3[0];
    for (int k = 0; k < 32; ++k) a += t2[k] * W3[k];
    out[g] = 1.f / (1.f + __expf(-a));
  }
}

// ---------------- launch ----------------

extern "C" void kernel_launch(void* const* d_in, const int* in_sizes, int n_in,
                              void* d_out, int out_size, void* d_ws, size_t ws_size,
                              hipStream_t stream) {
  const float* x = (const float*)d_in[0];
  const int* edge_index = (const int*)d_in[1];
  const int* batch = (const int*)d_in[2];
  const int N = in_sizes[0] / DH;
  const int E = in_sizes[1] / 2;
  const int G = out_size;
  const int* src = edge_index;
  const int* dst = edge_index + E;

  const float* in_Wq = (const float*)d_in[3];
  const float* in_bq = (const float*)d_in[4];
  const float* in_Wk = (const float*)d_in[5];
  const float* in_bk = (const float*)d_in[6];
  const float* in_Wv = (const float*)d_in[7];
  const float* in_bv = (const float*)d_in[8];
  const float* in_Ws = (const float*)d_in[9];
  const float* in_bs = (const float*)d_in[10];
  const float* in_Wbeta = (const float*)d_in[11];
  const float* blk_Wq = (const float*)d_in[12];
  const float* blk_bq = (const float*)d_in[13];
  const float* blk_Wk = (const float*)d_in[14];
  const float* blk_bk = (const float*)d_in[15];
  const float* blk_Wv = (const float*)d_in[16];
  const float* blk_bv = (const float*)d_in[17];
  const float* blk_Ws = (const float*)d_in[18];
  const float* blk_bs = (const float*)d_in[19];
  const float* blk_Wbeta = (const float*)d_in[20];

  // workspace carve (256B aligned)
  char* p = (char*)d_ws;
  auto take = [&](size_t bytes) { char* r = p; p += (bytes + 255) & ~(size_t)255; return r; };
  __hip_bfloat16* h0 = (__hip_bfloat16*)take((size_t)N * DH * 2);
  __hip_bfloat16* h1 = (__hip_bfloat16*)take((size_t)N * DH * 2);
  unsigned char* kvp = (unsigned char*)take((size_t)N * 256);
  unsigned short* xr = (unsigned short*)take((size_t)N * DH * 2);
  __hip_bfloat16* WT = (__hip_bfloat16*)take((size_t)512 * DH * 2);
  float* bcat = (float*)take(512 * 4);
  int* deg    = (int*)take((size_t)N * 4);
  int* off    = (int*)take((size_t)N * 4);
  int* csr    = (int*)take((size_t)E * 4);
  int* part   = (int*)take((size_t)E * 4);
  int* hist   = (int*)take((size_t)NB * NBK * 4);
  int* total  = (int*)take(NBK * 4);
  int* tstart = (int*)take(NBK * 4);
  int* bsumP  = (int*)take(512 * 4);
  int* gdeg   = (int*)take((size_t)G * 4);
  int* goff   = (int*)take((size_t)G * 4);
  int* bsum2  = (int*)take(512 * 4);
  (void)n_in;
  if ((size_t)(p - (char*)d_ws) > ws_size) return;

  const int NBUCK = (N + 127) >> 7;
  const int chunk = (E + NB - 1) / NB;
  int nb = (N + 255) / 256;
  int gb = (G + 255) / 256;

  // ---- atomic-free CSR build ----
  csr_p1<<<NB, 256, 0, stream>>>(dst, hist, E, chunk);
  csr_p2<<<NBK / 256, 256, 0, stream>>>(hist, total);
  scan1_kernel<<<NBK / 256, 256, 0, stream>>>(total, tstart, bsumP, NBK);
  scan2_kernel<<<1, 512, 0, stream>>>(bsumP, NBK / 256);
  scan3_kernel<<<NBK / 256, 256, 0, stream>>>(tstart, bsumP, NBK);
  csr_p3<<<NB, 256, 0, stream>>>(src, dst, hist, tstart, part, E, chunk);
  csr_p4<<<NBUCK, 256, 0, stream>>>(part, tstart, total, deg, off, csr, N);

  // ---- graph segments (batch is sorted) ----
  zero_i32<<<gb, 256, 0, stream>>>(gdeg, G);
  hist_kernel<<<nb, 256, 0, stream>>>(batch, gdeg, N);
  scan1_kernel<<<gb, 256, 0, stream>>>(gdeg, goff, bsum2, G);
  scan2_kernel<<<1, 512, 0, stream>>>(bsum2, gb);
  scan3_kernel<<<gb, 256, 0, stream>>>(goff, bsum2, G);

  cvt_bf16<<<(int)(((size_t)N * DH + 255) / 256), 256, 0, stream>>>(x, h0, N * DH);

  for (int l = 0; l < 4; ++l) {
    const float *Wq, *Wk, *Wv, *Ws, *bq, *bk, *bv, *bs, *Wb;
    if (l == 0) {
      Wq = in_Wq; Wk = in_Wk; Wv = in_Wv; Ws = in_Ws;
      bq = in_bq; bk = in_bk; bv = in_bv; bs = in_bs; Wb = in_Wbeta;
    } else {
      int m = l - 1;
      Wq = blk_Wq + (size_t)m * DH * DH; Wk = blk_Wk + (size_t)m * DH * DH;
      Wv = blk_Wv + (size_t)m * DH * DH; Ws = blk_Ws + (size_t)m * DH * DH;
      bq = blk_bq + (size_t)m * DH; bk = blk_bk + (size_t)m * DH;
      bv = blk_bv + (size_t)m * DH; bs = blk_bs + (size_t)m * DH;
      Wb = blk_Wbeta + (size_t)m * 3 * DH;
    }
    __hip_bfloat16* hin  = (l & 1) ? h1 : h0;
    __hip_bfloat16* qbuf = (l & 1) ? h0 : h1;
    pack_w_kernel<<<(512 * DH + 255) / 256, 256, 0, stream>>>(Wq, Wk, Wv, Ws, bq, bk, bv, bs, WT, bcat);
    gemm_qkvs<<<(N + 63) / 64, 256, 0, stream>>>((const short*)hin, (const short*)WT, bcat,
        (unsigned short*)qbuf, kvp, xr, N);
    attn_kernel<<<(N + 3) / 4, 256, 0, stream>>>((unsigned int*)qbuf, (const unsigned int*)kvp,
        (const unsigned int*)xr, off, deg, csr, Wb, N);
  }

  // after 4 layers h lives in h0
  poolmlp_kernel<<<G, 128, 0, stream>>>((const unsigned short*)h0, goff, gdeg,
      (const float*)d_in[21], (const float*)d_in[22],
      (const float*)d_in[23], (const float*)d_in[24],
      (const float*)d_in[25], (const float*)d_in[26],
      (float*)d_out);
}

// Round 6
// 790.189 us; speedup vs baseline: 2.7555x; 1.0751x over previous
//
#include <hip/hip_runtime.h>
#include <hip/hip_bf16.h>
#include <cstdint>

#define DH 128   // hidden dim
#define NB 256   // partition blocks for CSR build
#define NBK 1024 // max buckets (N <= 131072)

typedef __attribute__((ext_vector_type(8))) short short8;
typedef __attribute__((ext_vector_type(4))) float floatx4;
typedef __attribute__((ext_vector_type(2))) float floatx2;

__device__ __forceinline__ float bflo(unsigned u) { return __uint_as_float(u << 16); }
__device__ __forceinline__ float bfhi(unsigned u) { return __uint_as_float(u & 0xffff0000u); }

__device__ __forceinline__ unsigned pk_bf16(float a, float b) {
  return ((unsigned)__bfloat16_as_ushort(__float2bfloat16(b)) << 16)
       | (unsigned)__bfloat16_as_ushort(__float2bfloat16(a));
}

template<int CTRL>
__device__ __forceinline__ float dpp_add(float x) {
  int y = __builtin_amdgcn_update_dpp(0, __float_as_int(x), CTRL, 0xf, 0xf, true);
  return x + __int_as_float(y);
}

// ---------------- zero-fill ----------------

__global__ void zero_i32(int* __restrict__ p, int n) {
  int i = blockIdx.x * 256 + threadIdx.x;
  if (i < n) p[i] = 0;
}

// ---------------- fp32 -> bf16 convert ----------------

__global__ void cvt_bf16(const float* __restrict__ x, __hip_bfloat16* __restrict__ o, int n) {
  int i = blockIdx.x * 256 + threadIdx.x;
  if (i < n) o[i] = __float2bfloat16(x[i]);
}

// ---------------- scans (generic, reused) ----------------

__global__ void hist_kernel(const int* __restrict__ dst, int* __restrict__ deg, int E) {
  int e = blockIdx.x * 256 + threadIdx.x;
  if (e < E) atomicAdd(&deg[dst[e]], 1);
}

__global__ void scan1_kernel(const int* __restrict__ deg, int* __restrict__ off,
                             int* __restrict__ bsum, int n) {
  __shared__ int sh[256];
  int idx = blockIdx.x * 256 + threadIdx.x;
  int v = (idx < n) ? deg[idx] : 0;
  sh[threadIdx.x] = v;
  __syncthreads();
  for (int d = 1; d < 256; d <<= 1) {
    int x = (threadIdx.x >= (unsigned)d) ? sh[threadIdx.x - d] : 0;
    __syncthreads();
    sh[threadIdx.x] += x;
    __syncthreads();
  }
  if (idx < n) off[idx] = sh[threadIdx.x] - v;   // exclusive
  if (threadIdx.x == 255) bsum[blockIdx.x] = sh[255];
}

__global__ void scan2_kernel(int* __restrict__ bsum, int nb) {
  __shared__ int sh[512];
  int t = threadIdx.x;
  int v = (t < nb) ? bsum[t] : 0;
  sh[t] = v;
  __syncthreads();
  for (int d = 1; d < 512; d <<= 1) {
    int x = (t >= (unsigned)d) ? sh[t - d] : 0;
    __syncthreads();
    sh[t] += x;
    __syncthreads();
  }
  if (t < nb) bsum[t] = sh[t] - v;
}

__global__ void scan3_kernel(int* __restrict__ off, const int* __restrict__ bsum, int n) {
  int idx = blockIdx.x * 256 + threadIdx.x;
  if (idx < n) off[idx] += bsum[blockIdx.x];
}

// ---------------- atomic-free CSR build (counting sort by dst>>7) ----------------

__global__ __launch_bounds__(256)
void csr_p1(const int* __restrict__ dst, int* __restrict__ hist, int E, int chunk) {
  __shared__ int cnt[NBK];
  const int blk = blockIdx.x, tid = threadIdx.x;
  for (int c = tid; c < NBK; c += 256) cnt[c] = 0;
  __syncthreads();
  int base = blk * chunk;
  int end = base + chunk; if (end > E) end = E;
  for (int e = base + tid; e < end; e += 256) atomicAdd(&cnt[dst[e] >> 7], 1);
  __syncthreads();
  for (int c = tid; c < NBK; c += 256) hist[blk * NBK + c] = cnt[c];
}

__global__ __launch_bounds__(256)
void csr_p2(int* __restrict__ hist, int* __restrict__ total) {
  int b = blockIdx.x * 256 + threadIdx.x;   // bucket id
  int run = 0;
  for (int blk = 0; blk < NB; ++blk) {
    int v = hist[blk * NBK + b];
    hist[blk * NBK + b] = run;
    run += v;
  }
  total[b] = run;
}

__global__ __launch_bounds__(256)
void csr_p3(const int* __restrict__ src, const int* __restrict__ dst,
            const int* __restrict__ hist, const int* __restrict__ tstart,
            int* __restrict__ part, int E, int chunk) {
  __shared__ int cur[NBK];
  const int blk = blockIdx.x, tid = threadIdx.x;
  for (int c = tid; c < NBK; c += 256) cur[c] = hist[blk * NBK + c] + tstart[c];
  __syncthreads();
  int base = blk * chunk;
  int end = base + chunk; if (end > E) end = E;
  for (int e = base + tid; e < end; e += 256) {
    int d = dst[e];
    int b = d >> 7;
    int pos = atomicAdd(&cur[b], 1);     // LDS atomic
    part[pos] = (src[e] << 7) | (d & 127);
  }
}

__global__ __launch_bounds__(256)
void csr_p4(const int* __restrict__ part, const int* __restrict__ tstart,
            const int* __restrict__ total, int* __restrict__ deg,
            int* __restrict__ off, int* __restrict__ csr, int Nn) {
  __shared__ int lcnt[128], lscan[128], lcur[128];
  const int b = blockIdx.x, tid = threadIdx.x;
  const int p0 = tstart[b];
  const int m = total[b];
  if (tid < 128) lcnt[tid] = 0;
  __syncthreads();
  for (int k = tid; k < m; k += 256) atomicAdd(&lcnt[part[p0 + k] & 127], 1);
  __syncthreads();
  if (tid < 128) lscan[tid] = lcnt[tid];
  __syncthreads();
  for (int d = 1; d < 128; d <<= 1) {
    int v = 0;
    if (tid < 128 && tid >= d) v = lscan[tid - d];
    __syncthreads();
    if (tid < 128) lscan[tid] += v;
    __syncthreads();
  }
  if (tid < 128) {
    int ex = lscan[tid] - lcnt[tid];
    lcur[tid] = ex;
    int n = (b << 7) + tid;
    if (n < Nn) { deg[n] = lcnt[tid]; off[n] = p0 + ex; }
  }
  __syncthreads();
  for (int k = tid; k < m; k += 256) {
    int pk = part[p0 + k];
    int pos = p0 + atomicAdd(&lcur[pk & 127], 1);   // LDS atomic
    csr[pos] = pk >> 7;
  }
}

// ---------------- weight packing: WT[512][128] bf16 = [Wq|Wk|Wv|Ws]^T ----------------

__global__ void pack_w_kernel(const float* __restrict__ Wq, const float* __restrict__ Wk,
                              const float* __restrict__ Wv, const float* __restrict__ Ws,
                              const float* __restrict__ bq, const float* __restrict__ bk,
                              const float* __restrict__ bv, const float* __restrict__ bs,
                              __hip_bfloat16* __restrict__ WT, float* __restrict__ bcat) {
  int idx = blockIdx.x * 256 + threadIdx.x;
  if (idx < 512 * DH) {
    int c = idx >> 7, k = idx & 127;
    int which = c >> 7, cc = c & 127;
    const float* W = (which == 0) ? Wq : (which == 1) ? Wk : (which == 2) ? Wv : Ws;
    WT[idx] = __float2bfloat16(W[k * DH + cc]);
    if (k == 0) {
      const float* b = (which == 0) ? bq : (which == 1) ? bk : (which == 2) ? bv : bs;
      bcat[c] = b[cc];
    }
  }
}

// ---------------- fused QKVS GEMM (TRANSPOSED MFMA: D[wcol][node]) ----------------
// A-operand = WT rows (wcols), B-operand = X rows (nodes). Lane holds one node
// and 4 consecutive wcols -> every output is one 8B uint2 store. No LDS.
// wave0: q (mtiles 0-7); wave1: k 8-11 + v 16-19; wave2: k 12-15 + v 20-23;
// wave3: xr (24-31). kvp dword f = {k(2f),k(2f+1),v(2f),v(2f+1)} fp8.

__global__ __launch_bounds__(256)
void gemm_qkvs(const short* __restrict__ Xb, const short* __restrict__ WT,
               const float* __restrict__ bc,
               unsigned int* __restrict__ qout,
               unsigned int* __restrict__ kvp,
               unsigned int* __restrict__ xrout, int Nn) {
  const int row0 = blockIdx.x * 64;
  const int tid = threadIdx.x;
  const int w = tid >> 6, lane = tid & 63, quad = lane >> 4, l16 = lane & 15;

  // B-operand: X fragments, 4 node-tiles x 4 k-chunks (16B contiguous per lane)
  short8 xf[4][4];
#pragma unroll
  for (int nt = 0; nt < 4; ++nt) {
    int node = row0 + nt * 16 + l16; if (node >= Nn) node = Nn - 1;
#pragma unroll
    for (int kt = 0; kt < 4; ++kt)
      xf[nt][kt] = *(const short8*)&Xb[(size_t)node * 128 + kt * 32 + quad * 8];
  }

  if (w == 0 || w == 3) {
    unsigned int* outp = (w == 0) ? qout : xrout;
    const int mbase = (w == 0) ? 0 : 24;
#pragma unroll
    for (int i = 0; i < 8; ++i) {
      const int mt = mbase + i;
      short8 af[4];
#pragma unroll
      for (int kt = 0; kt < 4; ++kt)
        af[kt] = *(const short8*)&WT[(size_t)(mt * 16 + l16) * 128 + kt * 32 + quad * 8];
      float4 bias = *(const float4*)&bc[mt * 16 + quad * 4];
      const int wc = (i * 16 + quad * 4);   // col within 128-col segment
#pragma unroll
      for (int nt = 0; nt < 4; ++nt) {
        floatx4 acc = (floatx4){0.f, 0.f, 0.f, 0.f};
#pragma unroll
        for (int kt = 0; kt < 4; ++kt)
          acc = __builtin_amdgcn_mfma_f32_16x16x32_bf16(af[kt], xf[nt][kt], acc, 0, 0, 0);
        int node = row0 + nt * 16 + l16;
        if (node < Nn) {
          uint2 o;
          o.x = pk_bf16(acc[0] + bias.x, acc[1] + bias.y);
          o.y = pk_bf16(acc[2] + bias.z, acc[3] + bias.w);
          *(uint2*)&outp[(size_t)node * 64 + (wc >> 1)] = o;
        }
      }
    }
  } else {
    const int kb = 8 + (w - 1) * 4;    // k mtiles
    const int vb = 16 + (w - 1) * 4;   // v mtiles
#pragma unroll
    for (int i = 0; i < 4; ++i) {
      const int mk = kb + i, mv = vb + i;
      short8 afk[4], afv[4];
#pragma unroll
      for (int kt = 0; kt < 4; ++kt) {
        afk[kt] = *(const short8*)&WT[(size_t)(mk * 16 + l16) * 128 + kt * 32 + quad * 8];
        afv[kt] = *(const short8*)&WT[(size_t)(mv * 16 + l16) * 128 + kt * 32 + quad * 8];
      }
      float4 bk4 = *(const float4*)&bc[mk * 16 + quad * 4];
      float4 bv4 = *(const float4*)&bc[mv * 16 + quad * 4];
      const int krel = (w - 1) * 64 + i * 16 + quad * 4;   // col within k segment, 0..127
#pragma unroll
      for (int nt = 0; nt < 4; ++nt) {
        floatx4 ak = (floatx4){0.f, 0.f, 0.f, 0.f};
        floatx4 av = (floatx4){0.f, 0.f, 0.f, 0.f};
#pragma unroll
        for (int kt = 0; kt < 4; ++kt) {
          ak = __builtin_amdgcn_mfma_f32_16x16x32_bf16(afk[kt], xf[nt][kt], ak, 0, 0, 0);
          av = __builtin_amdgcn_mfma_f32_16x16x32_bf16(afv[kt], xf[nt][kt], av, 0, 0, 0);
        }
        int node = row0 + nt * 16 + l16;
        if (node < Nn) {
          int d0 = __builtin_amdgcn_cvt_pk_fp8_f32(ak[0] + bk4.x, ak[1] + bk4.y, 0, false);
          d0 = __builtin_amdgcn_cvt_pk_fp8_f32(av[0] + bv4.x, av[1] + bv4.y, d0, true);
          int d1 = __builtin_amdgcn_cvt_pk_fp8_f32(ak[2] + bk4.z, ak[3] + bk4.w, 0, false);
          d1 = __builtin_amdgcn_cvt_pk_fp8_f32(av[2] + bv4.z, av[3] + bv4.w, d1, true);
          uint2 o; o.x = (unsigned)d0; o.y = (unsigned)d1;
          *(uint2*)&kvp[(size_t)node * 64 + (krel >> 1)] = o;
        }
      }
    }
  }
}

// ---------------- attention: one WAVE per node, scalarized edge loop ------------

__global__ __launch_bounds__(256)
void attn_kernel(unsigned int* __restrict__ q_h, const unsigned int* __restrict__ kvp,
                 const unsigned int* __restrict__ xrb, const int* __restrict__ off,
                 const int* __restrict__ deg, const int* __restrict__ csr,
                 const float* __restrict__ Wb, int Nn) {
  int wv = __builtin_amdgcn_readfirstlane(threadIdx.x >> 6);
  int i = blockIdx.x * 4 + wv;
  if (i >= Nn) return;
  int l = threadIdx.x & 63;

  unsigned qp = q_h[(size_t)i * 64 + l];
  float q0 = bflo(qp), q1 = bfhi(qp);
  int e0 = off[i], e1 = e0 + deg[i];

  float den0 = 0.f, x00 = 0.f, x10 = 0.f;
  float den1 = 0.f, x01 = 0.f, x11 = 0.f;
  float den2 = 0.f, x02 = 0.f, x12 = 0.f;
  float den3 = 0.f, x03 = 0.f, x13 = 0.f;

  auto body = [&](int e, float& den, float& a0, float& a1) {
    int s = csr[e];
    int kq = (int)kvp[(size_t)s * 64 + l];
    floatx2 kk = __builtin_amdgcn_cvt_pk_f32_fp8(kq, false);   // bytes 0,1 = k0,k1
    floatx2 vv = __builtin_amdgcn_cvt_pk_f32_fp8(kq, true);    // bytes 2,3 = v0,v1
    float d = q0 * kk.x + q1 * kk.y;
    d = dpp_add<0x128>(d);   // row_ror:8
    d = dpp_add<0x124>(d);   // row_ror:4
    d = dpp_add<0x122>(d);   // row_ror:2
    d = dpp_add<0x121>(d);   // row_ror:1
    float p = __expf(d * 0.17677669529663687f);   // 1/sqrt(32)
    den += p; a0 += p * vv.x; a1 += p * vv.y;
  };

  int e = e0;
  for (; e + 3 < e1; e += 4) {
    body(e + 0, den0, x00, x10);
    body(e + 1, den1, x01, x11);
    body(e + 2, den2, x02, x12);
    body(e + 3, den3, x03, x13);
  }
  for (; e < e1; ++e) body(e, den0, x00, x10);

  float denom = den0 + den1 + den2 + den3 + 1e-16f;
  float o0 = (x00 + x01 + x02 + x03) / denom;
  float o1 = (x10 + x11 + x12 + x13) / denom;

  unsigned xp = xrb[(size_t)i * 64 + l];
  float xr0 = bflo(xp), xr1 = bfhi(xp);

  float c = o0 * Wb[2 * l] + o1 * Wb[2 * l + 1]
          + xr0 * Wb[128 + 2 * l] + xr1 * Wb[128 + 2 * l + 1]
          + (o0 - xr0) * Wb[256 + 2 * l] + (o1 - xr1) * Wb[256 + 2 * l + 1];
  c += __shfl_xor(c, 1);
  c += __shfl_xor(c, 2);
  c += __shfl_xor(c, 4);
  c += __shfl_xor(c, 8);
  c += __shfl_xor(c, 16);
  c += __shfl_xor(c, 32);
  float beta = 1.f / (1.f + __expf(-c));
  float h0 = fmaxf(beta * xr0 + (1.f - beta) * o0, 0.f);
  float h1 = fmaxf(beta * xr1 + (1.f - beta) * o1, 0.f);
  q_h[(size_t)i * 64 + l] = pk_bf16(h0, h1);
}

// ---------------- fused mean-pool + MLP ----------------

__global__ __launch_bounds__(128)
void poolmlp_kernel(const unsigned short* __restrict__ h, const int* __restrict__ goff,
                    const int* __restrict__ gdeg,
                    const float* __restrict__ W1, const float* __restrict__ b1,
                    const float* __restrict__ W2, const float* __restrict__ b2,
                    const float* __restrict__ W3, const float* __restrict__ b3,
                    float* __restrict__ out) {
  int g = blockIdx.x;
  int t = threadIdx.x;
  int n0 = goff[g], cnt = gdeg[g];
  float s = 0.f;
  for (int n = n0; n < n0 + cnt; ++n) s += bflo(h[(size_t)n * 128 + t]);
  __shared__ float gv[128];
  __shared__ float t1[64];
  __shared__ float t2[32];
  gv[t] = s / fmaxf((float)cnt, 1.0f);
  __syncthreads();
  if (t < 64) {
    float a = b1[t];
    for (int k = 0; k < 128; ++k) a += gv[k] * W1[k * 64 + t];
    t1[t] = fmaxf(a, 0.f);
  }
  __syncthreads();
  if (t < 32) {
    float a = b2[t];
    for (int k = 0; k < 64; ++k) a += t1[k] * W2[k * 32 + t];
    t2[t] = fmaxf(a, 0.f);
  }
  __syncthreads();
  if (t == 0) {
    float a = b3[0];
    for (int k = 0; k < 32; ++k) a += t2[k] * W3[k];
    out[g] = 1.f / (1.f + __expf(-a));
  }
}

// ---------------- launch ----------------

extern "C" void kernel_launch(void* const* d_in, const int* in_sizes, int n_in,
                              void* d_out, int out_size, void* d_ws, size_t ws_size,
                              hipStream_t stream) {
  const float* x = (const float*)d_in[0];
  const int* edge_index = (const int*)d_in[1];
  const int* batch = (const int*)d_in[2];
  const int N = in_sizes[0] / DH;
  const int E = in_sizes[1] / 2;
  const int G = out_size;
  const int* src = edge_index;
  const int* dst = edge_index + E;

  const float* in_Wq = (const float*)d_in[3];
  const float* in_bq = (const float*)d_in[4];
  const float* in_Wk = (const float*)d_in[5];
  const float* in_bk = (const float*)d_in[6];
  const float* in_Wv = (const float*)d_in[7];
  const float* in_bv = (const float*)d_in[8];
  const float* in_Ws = (const float*)d_in[9];
  const float* in_bs = (const float*)d_in[10];
  const float* in_Wbeta = (const float*)d_in[11];
  const float* blk_Wq = (const float*)d_in[12];
  const float* blk_bq = (const float*)d_in[13];
  const float* blk_Wk = (const float*)d_in[14];
  const float* blk_bk = (const float*)d_in[15];
  const float* blk_Wv = (const float*)d_in[16];
  const float* blk_bv = (const float*)d_in[17];
  const float* blk_Ws = (const float*)d_in[18];
  const float* blk_bs = (const float*)d_in[19];
  const float* blk_Wbeta = (const float*)d_in[20];

  // workspace carve (256B aligned)
  char* p = (char*)d_ws;
  auto take = [&](size_t bytes) { char* r = p; p += (bytes + 255) & ~(size_t)255; return r; };
  __hip_bfloat16* h0 = (__hip_bfloat16*)take((size_t)N * DH * 2);
  __hip_bfloat16* h1 = (__hip_bfloat16*)take((size_t)N * DH * 2);
  unsigned char* kvp = (unsigned char*)take((size_t)N * 256);
  unsigned short* xr = (unsigned short*)take((size_t)N * DH * 2);
  __hip_bfloat16* WT = (__hip_bfloat16*)take((size_t)512 * DH * 2);
  float* bcat = (float*)take(512 * 4);
  int* deg    = (int*)take((size_t)N * 4);
  int* off    = (int*)take((size_t)N * 4);
  int* csr    = (int*)take((size_t)E * 4);
  int* part   = (int*)take((size_t)E * 4);
  int* hist   = (int*)take((size_t)NB * NBK * 4);
  int* total  = (int*)take(NBK * 4);
  int* tstart = (int*)take(NBK * 4);
  int* bsumP  = (int*)take(512 * 4);
  int* gdeg   = (int*)take((size_t)G * 4);
  int* goff   = (int*)take((size_t)G * 4);
  int* bsum2  = (int*)take(512 * 4);
  (void)n_in;
  if ((size_t)(p - (char*)d_ws) > ws_size) return;

  const int NBUCK = (N + 127) >> 7;
  const int chunk = (E + NB - 1) / NB;
  int nb = (N + 255) / 256;
  int gb = (G + 255) / 256;

  // ---- atomic-free CSR build ----
  csr_p1<<<NB, 256, 0, stream>>>(dst, hist, E, chunk);
  csr_p2<<<NBK / 256, 256, 0, stream>>>(hist, total);
  scan1_kernel<<<NBK / 256, 256, 0, stream>>>(total, tstart, bsumP, NBK);
  scan2_kernel<<<1, 512, 0, stream>>>(bsumP, NBK / 256);
  scan3_kernel<<<NBK / 256, 256, 0, stream>>>(tstart, bsumP, NBK);
  csr_p3<<<NB, 256, 0, stream>>>(src, dst, hist, tstart, part, E, chunk);
  csr_p4<<<NBUCK, 256, 0, stream>>>(part, tstart, total, deg, off, csr, N);

  // ---- graph segments (batch is sorted) ----
  zero_i32<<<gb, 256, 0, stream>>>(gdeg, G);
  hist_kernel<<<nb, 256, 0, stream>>>(batch, gdeg, N);
  scan1_kernel<<<gb, 256, 0, stream>>>(gdeg, goff, bsum2, G);
  scan2_kernel<<<1, 512, 0, stream>>>(bsum2, gb);
  scan3_kernel<<<gb, 256, 0, stream>>>(goff, bsum2, G);

  cvt_bf16<<<(int)(((size_t)N * DH + 255) / 256), 256, 0, stream>>>(x, h0, N * DH);

  for (int l = 0; l < 4; ++l) {
    const float *Wq, *Wk, *Wv, *Ws, *bq, *bk, *bv, *bs, *Wb;
    if (l == 0) {
      Wq = in_Wq; Wk = in_Wk; Wv = in_Wv; Ws = in_Ws;
      bq = in_bq; bk = in_bk; bv = in_bv; bs = in_bs; Wb = in_Wbeta;
    } else {
      int m = l - 1;
      Wq = blk_Wq + (size_t)m * DH * DH; Wk = blk_Wk + (size_t)m * DH * DH;
      Wv = blk_Wv + (size_t)m * DH * DH; Ws = blk_Ws + (size_t)m * DH * DH;
      bq = blk_bq + (size_t)m * DH; bk = blk_bk + (size_t)m * DH;
      bv = blk_bv + (size_t)m * DH; bs = blk_bs + (size_t)m * DH;
      Wb = blk_Wbeta + (size_t)m * 3 * DH;
    }
    __hip_bfloat16* hin  = (l & 1) ? h1 : h0;
    __hip_bfloat16* qbuf = (l & 1) ? h0 : h1;
    pack_w_kernel<<<(512 * DH + 255) / 256, 256, 0, stream>>>(Wq, Wk, Wv, Ws, bq, bk, bv, bs, WT, bcat);
    gemm_qkvs<<<(N + 63) / 64, 256, 0, stream>>>((const short*)hin, (const short*)WT, bcat,
        (unsigned int*)qbuf, (unsigned int*)kvp, (unsigned int*)xr, N);
    attn_kernel<<<(N + 3) / 4, 256, 0, stream>>>((unsigned int*)qbuf, (const unsigned int*)kvp,
        (const unsigned int*)xr, off, deg, csr, Wb, N);
  }

  // after 4 layers h lives in h0
  poolmlp_kernel<<<G, 128, 0, stream>>>((const unsigned short*)h0, goff, gdeg,
      (const float*)d_in[21], (const float*)d_in[22],
      (const float*)d_in[23], (const float*)d_in[24],
      (const float*)d_in[25], (const float*)d_in[26],
      (float*)d_out);
}